// Round 5
// baseline (664.367 us; speedup 1.0000x reference)
//
#include <hip/hip_runtime.h>

// Problem dims (fixed)
#define B_DIM  2
#define C_DIM  8
#define F_DIM  1024
#define T_DIM  256
#define CH_DIM 32
#define FH_DIM 4096
#define BT_DIM 512   // B*T

typedef __bf16 bf16x8 __attribute__((ext_vector_type(8)));
typedef __bf16 bf16x4 __attribute__((ext_vector_type(4)));
typedef float  f32x4  __attribute__((ext_vector_type(4)));

__device__ __forceinline__ void async16(const void* g, void* l) {
  __builtin_amdgcn_global_load_lds(
      (const __attribute__((address_space(1))) unsigned int*)g,
      (__attribute__((address_space(3))) unsigned int*)l, 16, 0, 0);
}

// ---------------------------------------------------------------------------
// Kernel 1: LayerNorm over F (per b,c,t) + affine, written TRANSPOSED:
//   hn[c][b*T + t][f]  (bf16)
// ---------------------------------------------------------------------------
__global__ void ln_kernel(const float* __restrict__ x,
                          const float* __restrict__ lnw,
                          const float* __restrict__ lnb,
                          __bf16* __restrict__ hn) {
  const int tb = blockIdx.x;      // t-chunk of 16
  const int c  = blockIdx.y;
  const int b  = blockIdx.z;
  const int tid = threadIdx.x;
  const int tx = tid & 15, ty = tid >> 4;
  const int t0 = tb * 16;

  const float* xp = x + (size_t)(b * C_DIM + c) * F_DIM * T_DIM;

  float s = 0.f, s2 = 0.f;
  for (int f = ty; f < F_DIM; f += 16) {
    float v = xp[f * T_DIM + t0 + tx];
    s += v; s2 += v * v;
  }
  __shared__ float ps[16][16], ps2[16][16];
  __shared__ float mean_s[16], rstd_s[16];
  ps[ty][tx] = s; ps2[ty][tx] = s2;
  __syncthreads();
  if (tid < 16) {
    float a = 0.f, a2 = 0.f;
    for (int j = 0; j < 16; ++j) { a += ps[j][tid]; a2 += ps2[j][tid]; }
    float mu  = a * (1.0f / F_DIM);
    float var = a2 * (1.0f / F_DIM) - mu * mu;
    mean_s[tid] = mu;
    rstd_s[tid] = rsqrtf(var + 1e-8f);
  }
  __syncthreads();

  __shared__ float tile[64][17];
  __bf16* hp = hn + ((size_t)c * BT_DIM + b * T_DIM + t0) * F_DIM;
  for (int ff = 0; ff < 16; ++ff) {
    const int f0 = ff * 64;
#pragma unroll
    for (int it = 0; it < 4; ++it) {
      int e  = it * 256 + tid;
      int fi = e >> 4, ti = e & 15;
      float v = xp[(f0 + fi) * T_DIM + t0 + ti];
      v = (v - mean_s[ti]) * rstd_s[ti];
      v = v * lnw[c * F_DIM + f0 + fi] + lnb[c * F_DIM + f0 + fi];
      tile[fi][ti] = v;
    }
    __syncthreads();
#pragma unroll
    for (int it = 0; it < 4; ++it) {
      int e  = it * 256 + tid;
      int fx = e & 63, tw = e >> 6;
      hp[(size_t)tw * F_DIM + f0 + fx] = (__bf16)tile[fx][tw];
    }
    __syncthreads();
  }
}

// ---------------------------------------------------------------------------
// Kernel 2: 128x128-tile batched GEMM, BK=64, simple 2-phase double-buffer.
//   C[m][n] = sum_k A[m][k] * Bt[n][k]
//   A : fp32 weights, reg-staged fp32->bf16 (issue-early / write-late)
//   Bt: bf16 activations (k-minor), global_load_lds, pre-swizzled source
// LDS 64KB total -> 2 blocks/CU (m114 TLP hides the per-tile barrier drain).
// XOR swizzle: phys16Bslot = logical ^ (row&7)  (2-way conflicts = free).
// 256 thr = 4 waves (2m x 2n), wave tile 64x64, acc 4x4 frags.
// FIFO order per iter: A loads (8), then B loads (4); writeA's counted wait
// (vmcnt 4) leaves B in flight; __syncthreads drains before buffer swap.
// Grid 1024 (4 block-waves/CU), per-XCD batch grouping for L2 reuse.
// CT=true: per-wave LDS-transpose epilogue -> 128B-coalesced writes.
// ---------------------------------------------------------------------------
template<int TPB_BITS, bool CT>   // tiles-per-batch = 1<<TPB_BITS (mt x 4 nt)
__global__ __launch_bounds__(256, 2)
void gemm128(const float* __restrict__ A, const __bf16* __restrict__ Bm,
             __bf16* __restrict__ Co, const int M, const int K) {
  constexpr int NBPX = 128 >> TPB_BITS;   // batches per XCD
  const int bid = blockIdx.x;
  const int xcd = bid & 7, idx = bid >> 3;          // idx 0..127
  const int batch = xcd * NBPX + (idx >> TPB_BITS);
  const int tile  = idx & ((1 << TPB_BITS) - 1);
  const int mt = tile >> 2, nt = tile & 3;

  const int tid = threadIdx.x, lane = tid & 63, wid = tid >> 6;

  const float*  Ab = A  + (size_t)batch * M * K + (size_t)(mt * 128) * K;
  const __bf16* Bb = Bm + (size_t)batch * BT_DIM * K + (size_t)(nt * 128) * K;

  __shared__ __align__(16) __bf16 As[2][128 * 64];
  __shared__ __align__(16) __bf16 Bs[2][128 * 64];

  const int a_row  = tid >> 1;          // 0..127
  const int a_half = tid & 1;           // 32-float half of the 64-col row
  const int r7 = a_row & 7;
  const float* const aBase = Ab + (size_t)a_row * K + a_half * 32;

  const int b_row8 = lane >> 3;         // row within 8-row chunk (== row&7)
  const int b_swz  = (lane & 7) ^ b_row8;  // pre-swizzled 16B source slot

  const int wm = (wid >> 1) * 64, wn = (wid & 1) * 64;
  const int lr = lane & 15, khi = lane >> 4, lswz = lr & 7;

  f32x4 acc[4][4] = {};
  float4 sa[8];
  const int NT = K >> 6;

  auto issueA = [&](int tt) {
#pragma unroll
    for (int j = 0; j < 8; ++j)
      sa[j] = *(const float4*)(aBase + (size_t)tt * 64 + j * 4);
  };
  auto issueB = [&](int buf, int tt) {
#pragma unroll
    for (int j = 0; j < 4; ++j) {
      const int c = wid * 4 + j;        // 8-row chunk 0..15
      async16(Bb + (size_t)(c * 8 + b_row8) * K + (size_t)tt * 64 + (b_swz << 3),
              &Bs[buf][c * 512]);
    }
  };
  auto writeA = [&](int buf) {
    __bf16* dst = &As[buf][a_row * 64];
#pragma unroll
    for (int j = 0; j < 4; ++j) {
      const float4 u0 = sa[2 * j], u1 = sa[2 * j + 1];
      bf16x8 v;
      v[0]=(__bf16)u0.x; v[1]=(__bf16)u0.y; v[2]=(__bf16)u0.z; v[3]=(__bf16)u0.w;
      v[4]=(__bf16)u1.x; v[5]=(__bf16)u1.y; v[6]=(__bf16)u1.z; v[7]=(__bf16)u1.w;
      *(bf16x8*)(dst + (((a_half * 4 + j) ^ r7) << 3)) = v;
    }
  };
  auto compute = [&](int buf) {
#pragma unroll
    for (int kk = 0; kk < 2; ++kk) {
      const int slot = ((kk * 4 + khi) ^ lswz) << 3;
      bf16x8 af[4], bq[4];
#pragma unroll
      for (int mi = 0; mi < 4; ++mi)
        af[mi] = *(const bf16x8*)(&As[buf][(wm + mi * 16 + lr) * 64] + slot);
#pragma unroll
      for (int ni = 0; ni < 4; ++ni)
        bq[ni] = *(const bf16x8*)(&Bs[buf][(wn + ni * 16 + lr) * 64] + slot);
      __builtin_amdgcn_s_setprio(1);
#pragma unroll
      for (int mi = 0; mi < 4; ++mi)
#pragma unroll
        for (int ni = 0; ni < 4; ++ni)
          acc[mi][ni] = __builtin_amdgcn_mfma_f32_16x16x32_bf16(af[mi], bq[ni], acc[mi][ni], 0, 0, 0);
      __builtin_amdgcn_s_setprio(0);
    }
  };

  // prologue: tile 0 -> buf 0
  issueA(0);
  issueB(0, 0);
  writeA(0);            // counted wait for sa only; B stays in flight
  __syncthreads();

  int buf = 0;
  for (int t = 0; t < NT; ++t) {
    const int tn = (t + 1 < NT) ? t + 1 : t;   // last iter re-stages (L2-hot)
    issueA(tn);          // 8 A loads first (older in FIFO)
    issueB(buf ^ 1, tn); // 4 B loads after
    compute(buf);        // A-load latency hides under MFMA
    writeA(buf ^ 1);     // vmcnt(4): A retired, B outstanding
    __syncthreads();     // drain; co-resident block covers the stall
    buf ^= 1;
  }

  // ---- epilogue: C/D frag map col = lane&15, row = (lane>>4)*4 + reg ----
  const int colc = lane & 15;
  const int rowb = (lane >> 4) * 4;
  if (CT) {
    // per-wave LDS transpose -> 128B-coalesced writes to Co[batch][n][m]
    __bf16* T = ((__bf16*)As) + wid * 2048;   // 16 x 72 region (4KB/wave)
#pragma unroll
    for (int ni = 0; ni < 4; ++ni) {
#pragma unroll
      for (int mi = 0; mi < 4; ++mi)
#pragma unroll
        for (int r = 0; r < 4; ++r)
          T[colc * 72 + mi * 16 + rowb + r] = (__bf16)acc[mi][ni][r];
      const int mbase = mt * 128 + wm;
      __bf16* outp = Co + (size_t)batch * BT_DIM * M
                        + (size_t)(nt * 128 + wn + ni * 16) * M + mbase + lane;
#pragma unroll
      for (int r = 0; r < 16; ++r)
        outp[(size_t)r * M] = T[r * 72 + lane];
    }
  } else {
#pragma unroll
    for (int mi = 0; mi < 4; ++mi) {
#pragma unroll
      for (int ni = 0; ni < 4; ++ni) {
        const int m = mt * 128 + wm + mi * 16 + rowb;
        const int n = nt * 128 + wn + ni * 16 + colc;
#pragma unroll
        for (int r = 0; r < 4; ++r)
          Co[((size_t)batch * M + m + r) * BT_DIM + n] = (__bf16)acc[mi][ni][r];
      }
    }
  }
}

// ---------------------------------------------------------------------------
// Kernel 3: channel mix 8->32 + squared ReLU.
// ---------------------------------------------------------------------------
__global__ void mix1_kernel(const __bf16* __restrict__ Y1,
                            const float* __restrict__ dw1,
                            __bf16* __restrict__ h2) {
  const int gidx = blockIdx.x * 256 + threadIdx.x;
  const int g8 = gidx & 511, bt = gidx >> 9;
  const int g0 = g8 * 8;

  float y[C_DIM][8];
#pragma unroll
  for (int c = 0; c < C_DIM; ++c) {
    bf16x8 v = *(const bf16x8*)(Y1 + ((size_t)c * BT_DIM + bt) * FH_DIM + g0);
#pragma unroll
    for (int j = 0; j < 8; ++j) y[c][j] = (float)v[j];
  }
  for (int d = 0; d < CH_DIM; ++d) {
    float s[8] = {0.f,0.f,0.f,0.f,0.f,0.f,0.f,0.f};
#pragma unroll
    for (int c = 0; c < C_DIM; ++c) {
      const float wv = dw1[d * C_DIM + c];
#pragma unroll
      for (int j = 0; j < 8; ++j) s[j] += wv * y[c][j];
    }
    bf16x8 o;
#pragma unroll
    for (int j = 0; j < 8; ++j) {
      float r = s[j] > 0.f ? s[j] : 0.f;
      o[j] = (__bf16)(r * r);
    }
    *(bf16x8*)(h2 + ((size_t)d * BT_DIM + bt) * FH_DIM + g0) = o;
  }
}

// ---------------------------------------------------------------------------
// Kernel 4: channel mix 32->8 + residual.
// ---------------------------------------------------------------------------
__global__ void mix2_kernel(const float* __restrict__ x,
                            const __bf16* __restrict__ Y2,
                            const float* __restrict__ dw2,
                            float* __restrict__ out) {
  const int gidx = blockIdx.x * 256 + threadIdx.x;
  const int t4 = gidx & 63;
  const int f  = (gidx >> 6) & 1023;
  const int dd = (gidx >> 16) & 7;
  const int b  = gidx >> 19;
  const int t0 = t4 * 4;

  const size_t oidx = ((size_t)(b * C_DIM + dd) * F_DIM + f) * T_DIM + t0;
  float4 acc = *(const float4*)(x + oidx);
  for (int d = 0; d < CH_DIM; ++d) {
    const float wv = dw2[dd * CH_DIM + d];
    bf16x4 v = *(const bf16x4*)(Y2 + ((size_t)d * F_DIM + f) * BT_DIM + b * T_DIM + t0);
    acc.x += wv * (float)v[0];
    acc.y += wv * (float)v[1];
    acc.z += wv * (float)v[2];
    acc.w += wv * (float)v[3];
  }
  *(float4*)(out + oidx) = acc;
}

// ---------------------------------------------------------------------------
extern "C" void kernel_launch(void* const* d_in, const int* in_sizes, int n_in,
                              void* d_out, int out_size, void* d_ws, size_t ws_size,
                              hipStream_t stream) {
  const float* x   = (const float*)d_in[0];
  const float* lnw = (const float*)d_in[1];
  const float* lnb = (const float*)d_in[2];
  const float* pw1 = (const float*)d_in[3];
  const float* dw1 = (const float*)d_in[4];
  const float* pw2 = (const float*)d_in[5];
  const float* dw2 = (const float*)d_in[6];
  float* out = (float*)d_out;

  char* ws = (char*)d_ws;
  __bf16* hn = (__bf16*)(ws);                    // [C][512][F]    8 MB
  __bf16* Y1 = (__bf16*)(ws + (8ULL << 20));     // [C][512][Fh]  32 MB
  __bf16* h2 = (__bf16*)(ws + (40ULL << 20));    // [Ch][512][Fh] 128 MB
  __bf16* Y2 = (__bf16*)(ws);                    // [Ch][F][512]  32 MB (reuse)

  ln_kernel<<<dim3(T_DIM / 16, C_DIM, B_DIM), 256, 0, stream>>>(x, lnw, lnb, hn);
  // pw1: per c: [4096 x 1024] @ [1024 x 512]^T -> Y1^T [512][4096]
  gemm128<7, true><<<1024, 256, 0, stream>>>(pw1, hn, Y1, FH_DIM, F_DIM);
  mix1_kernel<<<(BT_DIM * (FH_DIM / 8)) / 256, 256, 0, stream>>>(Y1, dw1, h2);
  // pw2: per d: [1024 x 4096] @ [4096 x 512]^T -> Y2 [1024][512]
  gemm128<5, false><<<1024, 256, 0, stream>>>(pw2, h2, Y2, F_DIM, FH_DIM);
  mix2_kernel<<<(B_DIM * C_DIM * F_DIM * (T_DIM / 4)) / 256, 256, 0, stream>>>(x, Y2, dw2, out);
}

// Round 6
// 622.125 us; speedup vs baseline: 1.0679x; 1.0679x over previous
//
#include <hip/hip_runtime.h>

// Problem dims (fixed)
#define B_DIM  2
#define C_DIM  8
#define F_DIM  1024
#define T_DIM  256
#define CH_DIM 32
#define FH_DIM 4096
#define BT_DIM 512   // B*T

typedef __bf16 bf16x8 __attribute__((ext_vector_type(8)));
typedef __bf16 bf16x4 __attribute__((ext_vector_type(4)));
typedef float  f32x4  __attribute__((ext_vector_type(4)));

__device__ __forceinline__ void async16(const void* g, void* l) {
  __builtin_amdgcn_global_load_lds(
      (const __attribute__((address_space(1))) unsigned int*)g,
      (__attribute__((address_space(3))) unsigned int*)l, 16, 0, 0);
}

// ---------------------------------------------------------------------------
// Kernel 1: LayerNorm over F (per b,c,t) + affine, written TRANSPOSED:
//   hn[c][b*T + t][f]  (bf16)
// ---------------------------------------------------------------------------
__global__ void ln_kernel(const float* __restrict__ x,
                          const float* __restrict__ lnw,
                          const float* __restrict__ lnb,
                          __bf16* __restrict__ hn) {
  const int tb = blockIdx.x;      // t-chunk of 16
  const int c  = blockIdx.y;
  const int b  = blockIdx.z;
  const int tid = threadIdx.x;
  const int tx = tid & 15, ty = tid >> 4;
  const int t0 = tb * 16;

  const float* xp = x + (size_t)(b * C_DIM + c) * F_DIM * T_DIM;

  float s = 0.f, s2 = 0.f;
  for (int f = ty; f < F_DIM; f += 16) {
    float v = xp[f * T_DIM + t0 + tx];
    s += v; s2 += v * v;
  }
  __shared__ float ps[16][16], ps2[16][16];
  __shared__ float mean_s[16], rstd_s[16];
  ps[ty][tx] = s; ps2[ty][tx] = s2;
  __syncthreads();
  if (tid < 16) {
    float a = 0.f, a2 = 0.f;
    for (int j = 0; j < 16; ++j) { a += ps[j][tid]; a2 += ps2[j][tid]; }
    float mu  = a * (1.0f / F_DIM);
    float var = a2 * (1.0f / F_DIM) - mu * mu;
    mean_s[tid] = mu;
    rstd_s[tid] = rsqrtf(var + 1e-8f);
  }
  __syncthreads();

  __shared__ float tile[64][17];
  __bf16* hp = hn + ((size_t)c * BT_DIM + b * T_DIM + t0) * F_DIM;
  for (int ff = 0; ff < 16; ++ff) {
    const int f0 = ff * 64;
#pragma unroll
    for (int it = 0; it < 4; ++it) {
      int e  = it * 256 + tid;
      int fi = e >> 4, ti = e & 15;
      float v = xp[(f0 + fi) * T_DIM + t0 + ti];
      v = (v - mean_s[ti]) * rstd_s[ti];
      v = v * lnw[c * F_DIM + f0 + fi] + lnb[c * F_DIM + f0 + fi];
      tile[fi][ti] = v;
    }
    __syncthreads();
#pragma unroll
    for (int it = 0; it < 4; ++it) {
      int e  = it * 256 + tid;
      int fx = e & 63, tw = e >> 6;
      hp[(size_t)tw * F_DIM + f0 + fx] = (__bf16)tile[fx][tw];
    }
    __syncthreads();
  }
}

// ---------------------------------------------------------------------------
// Kernel 2a (pw1): R1-proven 128x128 tile, BK=32, single-buffered 16KB LDS,
// ~8 blocks/CU (TLP hides per-iter latency; short-K GEMM wants occupancy).
//   Y1^T[batch][n][m] = sum_k A[batch][m][k] * hn[batch][n][k]
// Epilogue: per-wave LDS transpose -> 128B-coalesced stores (fixes the 32B
// write-sector waste of the R1 original).
// ---------------------------------------------------------------------------
__global__ void gemm_pw1(const float* __restrict__ A,
                         const __bf16* __restrict__ Bmat,
                         __bf16* __restrict__ Co,
                         const int M, const int K) {
  const int bid = blockIdx.x;
  const int xcd = bid & 7;
  const int q   = bid >> 3;
  const int nt  = q & 3;
  const int idx = xcd * 32 + (q >> 2);
  const int batch = idx >> 5;       // 8 batches, one per XCD
  const int mt    = idx & 31;

  const int tid  = threadIdx.x;
  const int lane = tid & 63;
  const int wid  = tid >> 6;

  const float*  Ab = A    + (size_t)batch * M * K + (size_t)(mt * 128) * K;
  const __bf16* Bb = Bmat + (size_t)batch * BT_DIM * K + (size_t)(nt * 128) * K;

  __shared__ __align__(16) __bf16 S[8192];   // As = S[0..4095], Bs = S[4096..]
  __bf16* const As = S;
  __bf16* const Bs = S + 4096;

  f32x4 acc[4][4] = {};

  const int wm  = (wid >> 1) * 64;
  const int wn  = (wid & 1) * 64;
  const int lr  = lane & 15;
  const int lk8 = (lane >> 4) * 8;

  const int a_r = tid >> 3;          // + 32*i
  const int a_c = (tid & 7) * 4;
  const int b_r = wid * 32 + (lane >> 2);   // + 16*j
  const int b_c = (lane & 3) * 8;

  const int ksteps = K >> 5;
  for (int ks = 0; ks < ksteps; ++ks) {
    const int k0 = ks << 5;
    // A-tile: reg-staged fp32 -> bf16 -> LDS [128][32]
#pragma unroll
    for (int i = 0; i < 4; ++i) {
      const int row = a_r + 32 * i;
      float4 av = *(const float4*)(Ab + (size_t)row * K + k0 + a_c);
      bf16x4 bv;
      bv[0] = (__bf16)av.x; bv[1] = (__bf16)av.y;
      bv[2] = (__bf16)av.z; bv[3] = (__bf16)av.w;
      *(bf16x4*)(&As[row * 32 + a_c]) = bv;
    }
    // B-tile: async global->LDS, 16B/lane, linear [128][32]
#pragma unroll
    for (int j = 0; j < 2; ++j) {
      const __bf16* g = Bb + (size_t)(b_r + 16 * j) * K + k0 + b_c;
      async16(g, &Bs[(wid * 32 + 16 * j) * 32]);
    }
    __syncthreads();

    bf16x8 af[4], bfr[4];
#pragma unroll
    for (int mi = 0; mi < 4; ++mi)
      af[mi] = *(const bf16x8*)(&As[(wm + mi * 16 + lr) * 32 + lk8]);
#pragma unroll
    for (int ni = 0; ni < 4; ++ni)
      bfr[ni] = *(const bf16x8*)(&Bs[(wn + ni * 16 + lr) * 32 + lk8]);
#pragma unroll
    for (int mi = 0; mi < 4; ++mi)
#pragma unroll
      for (int ni = 0; ni < 4; ++ni)
        acc[mi][ni] = __builtin_amdgcn_mfma_f32_16x16x32_bf16(af[mi], bfr[ni], acc[mi][ni], 0, 0, 0);
    __syncthreads();
  }

  // epilogue: per-wave LDS transpose -> 128B-coalesced stores of Y1^T.
  // C/D frag map: col = lane&15, row = (lane>>4)*4 + reg.
  const int colc = lane & 15;
  const int rowb = (lane >> 4) * 4;
  __bf16* T = S + wid * 1152;        // 16 cols x 72 (64 m + 8 pad), per wave
  const int mbase = mt * 128 + wm;
#pragma unroll
  for (int ni = 0; ni < 4; ++ni) {
#pragma unroll
    for (int mi = 0; mi < 4; ++mi)
#pragma unroll
      for (int r = 0; r < 4; ++r)
        T[colc * 72 + mi * 16 + rowb + r] = (__bf16)acc[mi][ni][r];
    __bf16* outp = Co + (size_t)batch * BT_DIM * M
                      + (size_t)(nt * 128 + wn + ni * 16) * M + mbase + lane;
#pragma unroll
    for (int r16 = 0; r16 < 16; ++r16)
      outp[(size_t)r16 * M] = T[r16 * 72 + lane];
  }
}

// ---------------------------------------------------------------------------
// Kernel 2b (pw2): R5-proven 128x128 tile, BK=64, double-buffered 64KB LDS,
// 2 blocks/CU, issue-early/write-late, XOR swizzle. Measured ~115us (~floor).
// ---------------------------------------------------------------------------
template<int TPB_BITS, bool CT>   // tiles-per-batch = 1<<TPB_BITS (mt x 4 nt)
__global__ __launch_bounds__(256, 2)
void gemm128(const float* __restrict__ A, const __bf16* __restrict__ Bm,
             __bf16* __restrict__ Co, const int M, const int K) {
  constexpr int NBPX = 128 >> TPB_BITS;   // batches per XCD
  const int bid = blockIdx.x;
  const int xcd = bid & 7, idx = bid >> 3;          // idx 0..127
  const int batch = xcd * NBPX + (idx >> TPB_BITS);
  const int tile  = idx & ((1 << TPB_BITS) - 1);
  const int mt = tile >> 2, nt = tile & 3;

  const int tid = threadIdx.x, lane = tid & 63, wid = tid >> 6;

  const float*  Ab = A  + (size_t)batch * M * K + (size_t)(mt * 128) * K;
  const __bf16* Bb = Bm + (size_t)batch * BT_DIM * K + (size_t)(nt * 128) * K;

  __shared__ __align__(16) __bf16 As[2][128 * 64];
  __shared__ __align__(16) __bf16 Bs[2][128 * 64];

  const int a_row  = tid >> 1;          // 0..127
  const int a_half = tid & 1;           // 32-float half of the 64-col row
  const int r7 = a_row & 7;
  const float* const aBase = Ab + (size_t)a_row * K + a_half * 32;

  const int b_row8 = lane >> 3;         // row within 8-row chunk (== row&7)
  const int b_swz  = (lane & 7) ^ b_row8;  // pre-swizzled 16B source slot

  const int wm = (wid >> 1) * 64, wn = (wid & 1) * 64;
  const int lr = lane & 15, khi = lane >> 4, lswz = lr & 7;

  f32x4 acc[4][4] = {};
  float4 sa[8];
  const int NT = K >> 6;

  auto issueA = [&](int tt) {
#pragma unroll
    for (int j = 0; j < 8; ++j)
      sa[j] = *(const float4*)(aBase + (size_t)tt * 64 + j * 4);
  };
  auto issueB = [&](int buf, int tt) {
#pragma unroll
    for (int j = 0; j < 4; ++j) {
      const int c = wid * 4 + j;        // 8-row chunk 0..15
      async16(Bb + (size_t)(c * 8 + b_row8) * K + (size_t)tt * 64 + (b_swz << 3),
              &Bs[buf][c * 512]);
    }
  };
  auto writeA = [&](int buf) {
    __bf16* dst = &As[buf][a_row * 64];
#pragma unroll
    for (int j = 0; j < 4; ++j) {
      const float4 u0 = sa[2 * j], u1 = sa[2 * j + 1];
      bf16x8 v;
      v[0]=(__bf16)u0.x; v[1]=(__bf16)u0.y; v[2]=(__bf16)u0.z; v[3]=(__bf16)u0.w;
      v[4]=(__bf16)u1.x; v[5]=(__bf16)u1.y; v[6]=(__bf16)u1.z; v[7]=(__bf16)u1.w;
      *(bf16x8*)(dst + (((a_half * 4 + j) ^ r7) << 3)) = v;
    }
  };
  auto compute = [&](int buf) {
#pragma unroll
    for (int kk = 0; kk < 2; ++kk) {
      const int slot = ((kk * 4 + khi) ^ lswz) << 3;
      bf16x8 af[4], bq[4];
#pragma unroll
      for (int mi = 0; mi < 4; ++mi)
        af[mi] = *(const bf16x8*)(&As[buf][(wm + mi * 16 + lr) * 64] + slot);
#pragma unroll
      for (int ni = 0; ni < 4; ++ni)
        bq[ni] = *(const bf16x8*)(&Bs[buf][(wn + ni * 16 + lr) * 64] + slot);
      __builtin_amdgcn_s_setprio(1);
#pragma unroll
      for (int mi = 0; mi < 4; ++mi)
#pragma unroll
        for (int ni = 0; ni < 4; ++ni)
          acc[mi][ni] = __builtin_amdgcn_mfma_f32_16x16x32_bf16(af[mi], bq[ni], acc[mi][ni], 0, 0, 0);
      __builtin_amdgcn_s_setprio(0);
    }
  };

  // prologue: tile 0 -> buf 0
  issueA(0);
  issueB(0, 0);
  writeA(0);            // counted wait for sa only; B stays in flight
  __syncthreads();

  int buf = 0;
  for (int t = 0; t < NT; ++t) {
    const int tn = (t + 1 < NT) ? t + 1 : t;   // last iter re-stages (L2-hot)
    issueA(tn);          // 8 A loads first (older in FIFO)
    issueB(buf ^ 1, tn); // 4 B loads after
    compute(buf);        // A-load latency hides under MFMA
    writeA(buf ^ 1);     // vmcnt(4): A retired, B outstanding
    __syncthreads();     // drain; co-resident block covers the stall
    buf ^= 1;
  }

  // ---- epilogue: C/D frag map col = lane&15, row = (lane>>4)*4 + reg ----
  const int colc = lane & 15;
  const int rowb = (lane >> 4) * 4;
  if (CT) {
    __bf16* T = ((__bf16*)As) + wid * 2048;
#pragma unroll
    for (int ni = 0; ni < 4; ++ni) {
#pragma unroll
      for (int mi = 0; mi < 4; ++mi)
#pragma unroll
        for (int r = 0; r < 4; ++r)
          T[colc * 72 + mi * 16 + rowb + r] = (__bf16)acc[mi][ni][r];
      const int mbase = mt * 128 + wm;
      __bf16* outp = Co + (size_t)batch * BT_DIM * M
                        + (size_t)(nt * 128 + wn + ni * 16) * M + mbase + lane;
#pragma unroll
      for (int r = 0; r < 16; ++r)
        outp[(size_t)r * M] = T[r * 72 + lane];
    }
  } else {
#pragma unroll
    for (int mi = 0; mi < 4; ++mi) {
#pragma unroll
      for (int ni = 0; ni < 4; ++ni) {
        const int m = mt * 128 + wm + mi * 16 + rowb;
        const int n = nt * 128 + wn + ni * 16 + colc;
#pragma unroll
        for (int r = 0; r < 4; ++r)
          Co[((size_t)batch * M + m + r) * BT_DIM + n] = (__bf16)acc[mi][ni][r];
      }
    }
  }
}

// ---------------------------------------------------------------------------
// Kernel 3: channel mix 8->32 + squared ReLU.
// ---------------------------------------------------------------------------
__global__ void mix1_kernel(const __bf16* __restrict__ Y1,
                            const float* __restrict__ dw1,
                            __bf16* __restrict__ h2) {
  const int gidx = blockIdx.x * 256 + threadIdx.x;
  const int g8 = gidx & 511, bt = gidx >> 9;
  const int g0 = g8 * 8;

  float y[C_DIM][8];
#pragma unroll
  for (int c = 0; c < C_DIM; ++c) {
    bf16x8 v = *(const bf16x8*)(Y1 + ((size_t)c * BT_DIM + bt) * FH_DIM + g0);
#pragma unroll
    for (int j = 0; j < 8; ++j) y[c][j] = (float)v[j];
  }
  for (int d = 0; d < CH_DIM; ++d) {
    float s[8] = {0.f,0.f,0.f,0.f,0.f,0.f,0.f,0.f};
#pragma unroll
    for (int c = 0; c < C_DIM; ++c) {
      const float wv = dw1[d * C_DIM + c];
#pragma unroll
      for (int j = 0; j < 8; ++j) s[j] += wv * y[c][j];
    }
    bf16x8 o;
#pragma unroll
    for (int j = 0; j < 8; ++j) {
      float r = s[j] > 0.f ? s[j] : 0.f;
      o[j] = (__bf16)(r * r);
    }
    *(bf16x8*)(h2 + ((size_t)d * BT_DIM + bt) * FH_DIM + g0) = o;
  }
}

// ---------------------------------------------------------------------------
// Kernel 4: channel mix 32->8 + residual.
// ---------------------------------------------------------------------------
__global__ void mix2_kernel(const float* __restrict__ x,
                            const __bf16* __restrict__ Y2,
                            const float* __restrict__ dw2,
                            float* __restrict__ out) {
  const int gidx = blockIdx.x * 256 + threadIdx.x;
  const int t4 = gidx & 63;
  const int f  = (gidx >> 6) & 1023;
  const int dd = (gidx >> 16) & 7;
  const int b  = gidx >> 19;
  const int t0 = t4 * 4;

  const size_t oidx = ((size_t)(b * C_DIM + dd) * F_DIM + f) * T_DIM + t0;
  float4 acc = *(const float4*)(x + oidx);
  for (int d = 0; d < CH_DIM; ++d) {
    const float wv = dw2[dd * CH_DIM + d];
    bf16x4 v = *(const bf16x4*)(Y2 + ((size_t)d * F_DIM + f) * BT_DIM + b * T_DIM + t0);
    acc.x += wv * (float)v[0];
    acc.y += wv * (float)v[1];
    acc.z += wv * (float)v[2];
    acc.w += wv * (float)v[3];
  }
  *(float4*)(out + oidx) = acc;
}

// ---------------------------------------------------------------------------
extern "C" void kernel_launch(void* const* d_in, const int* in_sizes, int n_in,
                              void* d_out, int out_size, void* d_ws, size_t ws_size,
                              hipStream_t stream) {
  const float* x   = (const float*)d_in[0];
  const float* lnw = (const float*)d_in[1];
  const float* lnb = (const float*)d_in[2];
  const float* pw1 = (const float*)d_in[3];
  const float* dw1 = (const float*)d_in[4];
  const float* pw2 = (const float*)d_in[5];
  const float* dw2 = (const float*)d_in[6];
  float* out = (float*)d_out;

  char* ws = (char*)d_ws;
  __bf16* hn = (__bf16*)(ws);                    // [C][512][F]    8 MB
  __bf16* Y1 = (__bf16*)(ws + (8ULL << 20));     // [C][512][Fh]  32 MB
  __bf16* h2 = (__bf16*)(ws + (40ULL << 20));    // [Ch][512][Fh] 128 MB
  __bf16* Y2 = (__bf16*)(ws);                    // [Ch][F][512]  32 MB (reuse)

  ln_kernel<<<dim3(T_DIM / 16, C_DIM, B_DIM), 256, 0, stream>>>(x, lnw, lnb, hn);
  // pw1: per c: [4096 x 1024] @ [1024 x 512]^T -> Y1^T [512][4096]
  gemm_pw1<<<1024, 256, 0, stream>>>(pw1, hn, Y1, FH_DIM, F_DIM);
  mix1_kernel<<<(BT_DIM * (FH_DIM / 8)) / 256, 256, 0, stream>>>(Y1, dw1, h2);
  // pw2: per d: [1024 x 4096] @ [4096 x 512]^T -> Y2 [1024][512]
  gemm128<5, false><<<1024, 256, 0, stream>>>(pw2, h2, Y2, F_DIM, FH_DIM);
  mix2_kernel<<<(B_DIM * C_DIM * F_DIM * (T_DIM / 4)) / 256, 256, 0, stream>>>(x, Y2, dw2, out);
}

// Round 7
// 476.181 us; speedup vs baseline: 1.3952x; 1.3065x over previous
//
#include <hip/hip_runtime.h>

// Problem dims (fixed)
#define B_DIM  2
#define C_DIM  8
#define F_DIM  1024
#define T_DIM  256
#define CH_DIM 32
#define FH_DIM 4096
#define BT_DIM 512   // B*T

typedef __bf16 bf16x8 __attribute__((ext_vector_type(8)));
typedef __bf16 bf16x4 __attribute__((ext_vector_type(4)));
typedef float  f32x4  __attribute__((ext_vector_type(4)));

__device__ __forceinline__ void async16(const void* g, void* l) {
  __builtin_amdgcn_global_load_lds(
      (const __attribute__((address_space(1))) unsigned int*)g,
      (__attribute__((address_space(3))) unsigned int*)l, 16, 0, 0);
}

// ---------------------------------------------------------------------------
// Kernel 1: LayerNorm over F (per b,c,t) + affine, written TRANSPOSED:
//   hn[c][b*T + t][f]  (bf16)
// ---------------------------------------------------------------------------
__global__ void ln_kernel(const float* __restrict__ x,
                          const float* __restrict__ lnw,
                          const float* __restrict__ lnb,
                          __bf16* __restrict__ hn) {
  const int tb = blockIdx.x;      // t-chunk of 16
  const int c  = blockIdx.y;
  const int b  = blockIdx.z;
  const int tid = threadIdx.x;
  const int tx = tid & 15, ty = tid >> 4;
  const int t0 = tb * 16;

  const float* xp = x + (size_t)(b * C_DIM + c) * F_DIM * T_DIM;

  float s = 0.f, s2 = 0.f;
  for (int f = ty; f < F_DIM; f += 16) {
    float v = xp[f * T_DIM + t0 + tx];
    s += v; s2 += v * v;
  }
  __shared__ float ps[16][16], ps2[16][16];
  __shared__ float mean_s[16], rstd_s[16];
  ps[ty][tx] = s; ps2[ty][tx] = s2;
  __syncthreads();
  if (tid < 16) {
    float a = 0.f, a2 = 0.f;
    for (int j = 0; j < 16; ++j) { a += ps[j][tid]; a2 += ps2[j][tid]; }
    float mu  = a * (1.0f / F_DIM);
    float var = a2 * (1.0f / F_DIM) - mu * mu;
    mean_s[tid] = mu;
    rstd_s[tid] = rsqrtf(var + 1e-8f);
  }
  __syncthreads();

  __shared__ float tile[64][17];
  __bf16* hp = hn + ((size_t)c * BT_DIM + b * T_DIM + t0) * F_DIM;
  for (int ff = 0; ff < 16; ++ff) {
    const int f0 = ff * 64;
#pragma unroll
    for (int it = 0; it < 4; ++it) {
      int e  = it * 256 + tid;
      int fi = e >> 4, ti = e & 15;
      float v = xp[(f0 + fi) * T_DIM + t0 + ti];
      v = (v - mean_s[ti]) * rstd_s[ti];
      v = v * lnw[c * F_DIM + f0 + fi] + lnb[c * F_DIM + f0 + fi];
      tile[fi][ti] = v;
    }
    __syncthreads();
#pragma unroll
    for (int it = 0; it < 4; ++it) {
      int e  = it * 256 + tid;
      int fx = e & 63, tw = e >> 6;
      hp[(size_t)tw * F_DIM + f0 + fx] = (__bf16)tile[fx][tw];
    }
    __syncthreads();
  }
}

// ---------------------------------------------------------------------------
// Kernel 2a (pw1): UNCHANGED from round 6 (measured ~85-90us).
//   Y1^T[batch][n][m] = sum_k A[batch][m][k] * hn[batch][n][k]
// ---------------------------------------------------------------------------
__global__ void gemm_pw1(const float* __restrict__ A,
                         const __bf16* __restrict__ Bmat,
                         __bf16* __restrict__ Co,
                         const int M, const int K) {
  const int bid = blockIdx.x;
  const int xcd = bid & 7;
  const int q   = bid >> 3;
  const int nt  = q & 3;
  const int idx = xcd * 32 + (q >> 2);
  const int batch = idx >> 5;       // 8 batches, one per XCD
  const int mt    = idx & 31;

  const int tid  = threadIdx.x;
  const int lane = tid & 63;
  const int wid  = tid >> 6;

  const float*  Ab = A    + (size_t)batch * M * K + (size_t)(mt * 128) * K;
  const __bf16* Bb = Bmat + (size_t)batch * BT_DIM * K + (size_t)(nt * 128) * K;

  __shared__ __align__(16) __bf16 S[8192];   // As = S[0..4095], Bs = S[4096..]
  __bf16* const As = S;
  __bf16* const Bs = S + 4096;

  f32x4 acc[4][4] = {};

  const int wm  = (wid >> 1) * 64;
  const int wn  = (wid & 1) * 64;
  const int lr  = lane & 15;
  const int lk8 = (lane >> 4) * 8;

  const int a_r = tid >> 3;          // + 32*i
  const int a_c = (tid & 7) * 4;
  const int b_r = wid * 32 + (lane >> 2);   // + 16*j
  const int b_c = (lane & 3) * 8;

  const int ksteps = K >> 5;
  for (int ks = 0; ks < ksteps; ++ks) {
    const int k0 = ks << 5;
#pragma unroll
    for (int i = 0; i < 4; ++i) {
      const int row = a_r + 32 * i;
      float4 av = *(const float4*)(Ab + (size_t)row * K + k0 + a_c);
      bf16x4 bv;
      bv[0] = (__bf16)av.x; bv[1] = (__bf16)av.y;
      bv[2] = (__bf16)av.z; bv[3] = (__bf16)av.w;
      *(bf16x4*)(&As[row * 32 + a_c]) = bv;
    }
#pragma unroll
    for (int j = 0; j < 2; ++j) {
      const __bf16* g = Bb + (size_t)(b_r + 16 * j) * K + k0 + b_c;
      async16(g, &Bs[(wid * 32 + 16 * j) * 32]);
    }
    __syncthreads();

    bf16x8 af[4], bfr[4];
#pragma unroll
    for (int mi = 0; mi < 4; ++mi)
      af[mi] = *(const bf16x8*)(&As[(wm + mi * 16 + lr) * 32 + lk8]);
#pragma unroll
    for (int ni = 0; ni < 4; ++ni)
      bfr[ni] = *(const bf16x8*)(&Bs[(wn + ni * 16 + lr) * 32 + lk8]);
#pragma unroll
    for (int mi = 0; mi < 4; ++mi)
#pragma unroll
      for (int ni = 0; ni < 4; ++ni)
        acc[mi][ni] = __builtin_amdgcn_mfma_f32_16x16x32_bf16(af[mi], bfr[ni], acc[mi][ni], 0, 0, 0);
    __syncthreads();
  }

  // epilogue: per-wave LDS transpose -> 128B-coalesced stores of Y1^T.
  const int colc = lane & 15;
  const int rowb = (lane >> 4) * 4;
  __bf16* T = S + wid * 1152;        // 16 cols x 72, per wave
  const int mbase = mt * 128 + wm;
#pragma unroll
  for (int ni = 0; ni < 4; ++ni) {
#pragma unroll
    for (int mi = 0; mi < 4; ++mi)
#pragma unroll
      for (int r = 0; r < 4; ++r)
        T[colc * 72 + mi * 16 + rowb + r] = (__bf16)acc[mi][ni][r];
    __bf16* outp = Co + (size_t)batch * BT_DIM * M
                      + (size_t)(nt * 128 + wn + ni * 16) * M + mbase + lane;
#pragma unroll
    for (int r16 = 0; r16 < 16; ++r16)
      outp[(size_t)r16 * M] = T[r16 * 72 + lane];
  }
}

// ---------------------------------------------------------------------------
// Kernel 2b (pw2): NEW this round. R1-lineage BK=32 skeleton +
//  - double-buffered 32KB LDS (-> ~4 blocks/CU TLP)
//  - fully-coalesced issue-early A (8 rows x 128B contiguous per instr,
//    4 float4 regs only)
//  - async-B prefetch (global_load_lds) into next buffer before compute
//  - XOR swizzle slot^((row>>1)&3) both sides (2 lanes/bank on all access)
//   Y2[batch][m][n] = sum_k A[batch][m][k] * h2[batch][n][k]
// Grid 1024 (batch 32 x mt 8 x nt 4), 256 thr (4 waves 2Mx2N).
// ---------------------------------------------------------------------------
__global__ __launch_bounds__(256, 3)
void gemm_pw2(const float* __restrict__ A, const __bf16* __restrict__ Bm,
              __bf16* __restrict__ Co) {
  const int M = F_DIM, K = FH_DIM;   // 1024, 4096
  const int bid = blockIdx.x;
  const int xcd = bid & 7, idx = bid >> 3;     // idx 0..127
  const int batch = xcd * 4 + (idx >> 5);      // 32 batches, 4 per XCD
  const int tile  = idx & 31;
  const int mt = tile >> 2, nt = tile & 3;     // 8 mt x 4 nt

  const int tid = threadIdx.x, lane = tid & 63, wid = tid >> 6;

  const float*  Ab = A  + (size_t)batch * M * K + (size_t)(mt * 128) * K;
  const __bf16* Bb = Bm + (size_t)batch * BT_DIM * K + (size_t)(nt * 128) * K;

  __shared__ __align__(16) __bf16 As[2][128 * 32];
  __shared__ __align__(16) __bf16 Bs[2][128 * 32];

  // A staging: 4 float4/thread; per instr: 8 rows x 128B contiguous (coalesced)
  const int a_r  = tid >> 3;         // rows a_r + 32*i
  const int a_c8 = tid & 7;          // 16B chunk within the 128B row

  const int wm = (wid >> 1) * 64, wn = (wid & 1) * 64;
  const int lr = lane & 15, khi = lane >> 4;
  const int lswz = (lr >> 1) & 3;    // (row>>1)&3 for row == lr (mod 16)

  f32x4 acc[4][4] = {};
  float4 sa[4];
  const int NT = K >> 5;   // 128

  auto issueA = [&](int tt) {
#pragma unroll
    for (int i = 0; i < 4; ++i)
      sa[i] = *(const float4*)(Ab + (size_t)(a_r + 32 * i) * K + tt * 32 + a_c8 * 4);
  };
  auto writeA = [&](int buf) {
#pragma unroll
    for (int i = 0; i < 4; ++i) {
      const int row = a_r + 32 * i;
      bf16x4 v;
      v[0] = (__bf16)sa[i].x; v[1] = (__bf16)sa[i].y;
      v[2] = (__bf16)sa[i].z; v[3] = (__bf16)sa[i].w;
      const int slot = (a_c8 >> 1) ^ ((row >> 1) & 3);
      *(bf16x4*)(&As[buf][row * 32 + slot * 8 + (a_c8 & 1) * 4]) = v;
    }
  };
  auto issueB = [&](int buf, int tt) {
#pragma unroll
    for (int j = 0; j < 2; ++j) {
      const int chunk = wid * 2 + j;               // 0..7, 16 rows each
      const int r = chunk * 16 + (lane >> 2);
      const int s = (lane & 3) ^ ((r >> 1) & 3);   // pre-swizzled source slot
      async16(Bb + (size_t)r * K + (size_t)tt * 32 + s * 8,
              &Bs[buf][chunk * 512]);              // linear dest, lane*16 auto
    }
  };
  auto compute = [&](int buf) {
    bf16x8 af[4], bq[4];
    const int soff = (khi ^ lswz) * 8;
#pragma unroll
    for (int mi = 0; mi < 4; ++mi)
      af[mi] = *(const bf16x8*)(&As[buf][(wm + mi * 16 + lr) * 32 + soff]);
#pragma unroll
    for (int ni = 0; ni < 4; ++ni)
      bq[ni] = *(const bf16x8*)(&Bs[buf][(wn + ni * 16 + lr) * 32 + soff]);
    __builtin_amdgcn_s_setprio(1);
#pragma unroll
    for (int mi = 0; mi < 4; ++mi)
#pragma unroll
      for (int ni = 0; ni < 4; ++ni)
        acc[mi][ni] = __builtin_amdgcn_mfma_f32_16x16x32_bf16(af[mi], bq[ni], acc[mi][ni], 0, 0, 0);
    __builtin_amdgcn_s_setprio(0);
  };

  // prologue: tile 0 -> buf 0
  issueA(0);
  issueB(0, 0);
  writeA(0);           // compiler: counted vmcnt for sa; B stays in flight
  __syncthreads();

  int buf = 0;
  for (int t = 0; t < NT; ++t) {
    const int tn = (t + 1 < NT) ? t + 1 : t;  // last iter re-stages (L2-hot)
    issueA(tn);          // 4 coalesced A loads (older in FIFO)
    issueB(buf ^ 1, tn); // 2 async16 B loads
    compute(buf);        // A latency hides under ds_read+MFMA
    writeA(buf ^ 1);     // counted vmcnt: A retired, B outstanding
    __syncthreads();     // drain; 3-4 co-resident blocks cover the stall
    buf ^= 1;
  }

  // epilogue: C/D frag map col = lane&15, row = (lane>>4)*4 + reg
  const int colc = lane & 15;
  const int rowb = (lane >> 4) * 4;
#pragma unroll
  for (int mi = 0; mi < 4; ++mi) {
#pragma unroll
    for (int ni = 0; ni < 4; ++ni) {
      const int m = mt * 128 + wm + mi * 16 + rowb;
      const int n = nt * 128 + wn + ni * 16 + colc;
#pragma unroll
      for (int r = 0; r < 4; ++r)
        Co[((size_t)batch * M + m + r) * BT_DIM + n] = (__bf16)acc[mi][ni][r];
    }
  }
}

// ---------------------------------------------------------------------------
// Kernel 3: channel mix 8->32 + squared ReLU.
// ---------------------------------------------------------------------------
__global__ void mix1_kernel(const __bf16* __restrict__ Y1,
                            const float* __restrict__ dw1,
                            __bf16* __restrict__ h2) {
  const int gidx = blockIdx.x * 256 + threadIdx.x;
  const int g8 = gidx & 511, bt = gidx >> 9;
  const int g0 = g8 * 8;

  float y[C_DIM][8];
#pragma unroll
  for (int c = 0; c < C_DIM; ++c) {
    bf16x8 v = *(const bf16x8*)(Y1 + ((size_t)c * BT_DIM + bt) * FH_DIM + g0);
#pragma unroll
    for (int j = 0; j < 8; ++j) y[c][j] = (float)v[j];
  }
  for (int d = 0; d < CH_DIM; ++d) {
    float s[8] = {0.f,0.f,0.f,0.f,0.f,0.f,0.f,0.f};
#pragma unroll
    for (int c = 0; c < C_DIM; ++c) {
      const float wv = dw1[d * C_DIM + c];
#pragma unroll
      for (int j = 0; j < 8; ++j) s[j] += wv * y[c][j];
    }
    bf16x8 o;
#pragma unroll
    for (int j = 0; j < 8; ++j) {
      float r = s[j] > 0.f ? s[j] : 0.f;
      o[j] = (__bf16)(r * r);
    }
    *(bf16x8*)(h2 + ((size_t)d * BT_DIM + bt) * FH_DIM + g0) = o;
  }
}

// ---------------------------------------------------------------------------
// Kernel 4: channel mix 32->8 + residual.
// ---------------------------------------------------------------------------
__global__ void mix2_kernel(const float* __restrict__ x,
                            const __bf16* __restrict__ Y2,
                            const float* __restrict__ dw2,
                            float* __restrict__ out) {
  const int gidx = blockIdx.x * 256 + threadIdx.x;
  const int t4 = gidx & 63;
  const int f  = (gidx >> 6) & 1023;
  const int dd = (gidx >> 16) & 7;
  const int b  = gidx >> 19;
  const int t0 = t4 * 4;

  const size_t oidx = ((size_t)(b * C_DIM + dd) * F_DIM + f) * T_DIM + t0;
  float4 acc = *(const float4*)(x + oidx);
  for (int d = 0; d < CH_DIM; ++d) {
    const float wv = dw2[dd * CH_DIM + d];
    bf16x4 v = *(const bf16x4*)(Y2 + ((size_t)d * F_DIM + f) * BT_DIM + b * T_DIM + t0);
    acc.x += wv * (float)v[0];
    acc.y += wv * (float)v[1];
    acc.z += wv * (float)v[2];
    acc.w += wv * (float)v[3];
  }
  *(float4*)(out + oidx) = acc;
}

// ---------------------------------------------------------------------------
extern "C" void kernel_launch(void* const* d_in, const int* in_sizes, int n_in,
                              void* d_out, int out_size, void* d_ws, size_t ws_size,
                              hipStream_t stream) {
  const float* x   = (const float*)d_in[0];
  const float* lnw = (const float*)d_in[1];
  const float* lnb = (const float*)d_in[2];
  const float* pw1 = (const float*)d_in[3];
  const float* dw1 = (const float*)d_in[4];
  const float* pw2 = (const float*)d_in[5];
  const float* dw2 = (const float*)d_in[6];
  float* out = (float*)d_out;

  char* ws = (char*)d_ws;
  __bf16* hn = (__bf16*)(ws);                    // [C][512][F]    8 MB
  __bf16* Y1 = (__bf16*)(ws + (8ULL << 20));     // [C][512][Fh]  32 MB
  __bf16* h2 = (__bf16*)(ws + (40ULL << 20));    // [Ch][512][Fh] 128 MB
  __bf16* Y2 = (__bf16*)(ws);                    // [Ch][F][512]  32 MB (reuse)

  ln_kernel<<<dim3(T_DIM / 16, C_DIM, B_DIM), 256, 0, stream>>>(x, lnw, lnb, hn);
  // pw1: per c: [4096 x 1024] @ [1024 x 512]^T -> Y1^T [512][4096]
  gemm_pw1<<<1024, 256, 0, stream>>>(pw1, hn, Y1, FH_DIM, F_DIM);
  mix1_kernel<<<(BT_DIM * (FH_DIM / 8)) / 256, 256, 0, stream>>>(Y1, dw1, h2);
  // pw2: per d: [1024 x 4096] @ [4096 x 512]^T -> Y2 [1024][512]
  gemm_pw2<<<1024, 256, 0, stream>>>(pw2, h2, Y2);
  mix2_kernel<<<(B_DIM * C_DIM * F_DIM * (T_DIM / 4)) / 256, 256, 0, stream>>>(x, Y2, dw2, out);
}

// Round 8
// 389.153 us; speedup vs baseline: 1.7072x; 1.2236x over previous
//
#include <hip/hip_runtime.h>

// Problem dims (fixed)
#define B_DIM  2
#define C_DIM  8
#define F_DIM  1024
#define T_DIM  256
#define CH_DIM 32
#define FH_DIM 4096
#define BT_DIM 512   // B*T

typedef __bf16 bf16x8 __attribute__((ext_vector_type(8)));
typedef __bf16 bf16x4 __attribute__((ext_vector_type(4)));
typedef float  f32x4  __attribute__((ext_vector_type(4)));

__device__ __forceinline__ void async16(const void* g, void* l) {
  __builtin_amdgcn_global_load_lds(
      (const __attribute__((address_space(1))) unsigned int*)g,
      (__attribute__((address_space(3))) unsigned int*)l, 16, 0, 0);
}

// ---------------------------------------------------------------------------
// Kernel 1: LayerNorm over F (per b,c,t) + affine, written TRANSPOSED:
//   hn[c][b*T + t][f]  (bf16)
// ---------------------------------------------------------------------------
__global__ void ln_kernel(const float* __restrict__ x,
                          const float* __restrict__ lnw,
                          const float* __restrict__ lnb,
                          __bf16* __restrict__ hn) {
  const int tb = blockIdx.x;      // t-chunk of 16
  const int c  = blockIdx.y;
  const int b  = blockIdx.z;
  const int tid = threadIdx.x;
  const int tx = tid & 15, ty = tid >> 4;
  const int t0 = tb * 16;

  const float* xp = x + (size_t)(b * C_DIM + c) * F_DIM * T_DIM;

  float s = 0.f, s2 = 0.f;
  for (int f = ty; f < F_DIM; f += 16) {
    float v = xp[f * T_DIM + t0 + tx];
    s += v; s2 += v * v;
  }
  __shared__ float ps[16][16], ps2[16][16];
  __shared__ float mean_s[16], rstd_s[16];
  ps[ty][tx] = s; ps2[ty][tx] = s2;
  __syncthreads();
  if (tid < 16) {
    float a = 0.f, a2 = 0.f;
    for (int j = 0; j < 16; ++j) { a += ps[j][tid]; a2 += ps2[j][tid]; }
    float mu  = a * (1.0f / F_DIM);
    float var = a2 * (1.0f / F_DIM) - mu * mu;
    mean_s[tid] = mu;
    rstd_s[tid] = rsqrtf(var + 1e-8f);
  }
  __syncthreads();

  __shared__ float tile[64][17];
  __bf16* hp = hn + ((size_t)c * BT_DIM + b * T_DIM + t0) * F_DIM;
  for (int ff = 0; ff < 16; ++ff) {
    const int f0 = ff * 64;
#pragma unroll
    for (int it = 0; it < 4; ++it) {
      int e  = it * 256 + tid;
      int fi = e >> 4, ti = e & 15;
      float v = xp[(f0 + fi) * T_DIM + t0 + ti];
      v = (v - mean_s[ti]) * rstd_s[ti];
      v = v * lnw[c * F_DIM + f0 + fi] + lnb[c * F_DIM + f0 + fi];
      tile[fi][ti] = v;
    }
    __syncthreads();
#pragma unroll
    for (int it = 0; it < 4; ++it) {
      int e  = it * 256 + tid;
      int fx = e & 63, tw = e >> 6;
      hp[(size_t)tw * F_DIM + f0 + fx] = (__bf16)tile[fx][tw];
    }
    __syncthreads();
  }
}

// ---------------------------------------------------------------------------
// Kernel 2: BM=128 x BN=512 (full N) batched GEMM, BK=32, dbuf, 8 waves.
//   C[m][n] = sum_k A[m][k] * Bt[n][k]
//   A : fp32 [batch][M][K] weights, read from HBM EXACTLY ONCE (no nt split),
//       reg-staged (2 float4/thr) -> cvt -> bf16x8 ds_write, swizzled
//   Bt: bf16 [batch][512][K] activations, global_load_lds, pre-swizzled src
// LDS 80KB dynamic: A dbuf 2x8KB + B dbuf 2x32KB.
// Per iter: 32 MFMA/wave (~1200cy cover per SIMD) vs one vmcnt(0) drain of
// B-loads issued a full compute-phase earlier -> drain nearly free.
// One raw s_barrier per iter. XOR swizzle slot^((row>>1)&3) both sides.
// Grid 256 (1/CU): batch = xcd*(32>>MTBITS) + idx>>MTBITS (B panel L2-local).
// CT=true: per-wave LDS-transpose epilogue (128B-coalesced Y1^T stores).
// ---------------------------------------------------------------------------
template<int MTBITS, bool CT>
__global__ __launch_bounds__(512, 2)
void gemm_bn512(const float* __restrict__ A, const __bf16* __restrict__ Bm,
                __bf16* __restrict__ Co, const int M, const int K) {
  const int bid = blockIdx.x;
  const int xcd = bid & 7, idx = bid >> 3;
  const int batch = xcd * (32 >> MTBITS) + (idx >> MTBITS);
  const int mt    = idx & ((1 << MTBITS) - 1);

  const int tid = threadIdx.x, lane = tid & 63, wid = tid >> 6;

  const float*  Ab = A  + (size_t)batch * M * K + (size_t)(mt * 128) * K;
  const __bf16* Bb = Bm + (size_t)batch * BT_DIM * K;

  extern __shared__ __align__(16) char smem[];
  __bf16* const AS = (__bf16*)smem;              // 2 x 4096 elems (8KB each)
  __bf16* const BS = (__bf16*)(smem + 16384);    // 2 x 16384 elems (32KB each)

  // A staging: row = tid>>2 (0..127), q = tid&3 -> 8 floats at cols q*8..q*8+7
  const int a_r = tid >> 2, a_q = tid & 3;
  const int a_swz = a_q ^ ((a_r >> 1) & 3);
  const float* const aBase = Ab + (size_t)a_r * K + a_q * 8;

  // B staging: wave rows [wid*64, wid*64+64), 4 async16 of 16 rows each
  const int b_r0 = wid * 64 + (lane >> 2);        // + j*16
  const int b_s  = (lane & 3) ^ ((lane >> 3) & 3); // pre-swizzled source slot

  const int wm = wid >> 2, wn = wid & 3;   // 2 m-halves x 4 n-quarters
  const int lr = lane & 15, khi = lane >> 4;
  const int rsw = (lr >> 1) & 3;

  f32x4 acc[4][8] = {};
  float4 sa[2];
  const int NT = K >> 5;

  auto issueA = [&](int tt) {
    sa[0] = *(const float4*)(aBase + (size_t)tt * 32);
    sa[1] = *(const float4*)(aBase + (size_t)tt * 32 + 4);
  };
  auto writeA = [&](int buf) {
    bf16x8 v;
    v[0]=(__bf16)sa[0].x; v[1]=(__bf16)sa[0].y; v[2]=(__bf16)sa[0].z; v[3]=(__bf16)sa[0].w;
    v[4]=(__bf16)sa[1].x; v[5]=(__bf16)sa[1].y; v[6]=(__bf16)sa[1].z; v[7]=(__bf16)sa[1].w;
    *(bf16x8*)(AS + buf * 4096 + a_r * 32 + a_swz * 8) = v;
  };
  auto issueB = [&](int buf, int tt) {
#pragma unroll
    for (int j = 0; j < 4; ++j) {
      const int r = b_r0 + j * 16;
      async16(Bb + (size_t)r * K + (size_t)tt * 32 + b_s * 8,
              BS + buf * 16384 + (wid * 64 + j * 16) * 32);
    }
  };
  auto compute = [&](int buf) {
    const __bf16* As = AS + buf * 4096;
    const __bf16* Bs = BS + buf * 16384;
    const int so = (khi ^ rsw) << 3;
    bf16x8 af[4];
#pragma unroll
    for (int mi = 0; mi < 4; ++mi)
      af[mi] = *(const bf16x8*)(As + (wm * 64 + mi * 16 + lr) * 32 + so);
#pragma unroll
    for (int h = 0; h < 2; ++h) {
      bf16x8 bq[4];
#pragma unroll
      for (int nj = 0; nj < 4; ++nj)
        bq[nj] = *(const bf16x8*)(Bs + (wn * 128 + (h * 4 + nj) * 16 + lr) * 32 + so);
      __builtin_amdgcn_s_setprio(1);
#pragma unroll
      for (int mi = 0; mi < 4; ++mi)
#pragma unroll
        for (int nj = 0; nj < 4; ++nj)
          acc[mi][h * 4 + nj] =
              __builtin_amdgcn_mfma_f32_16x16x32_bf16(af[mi], bq[nj], acc[mi][h * 4 + nj], 0, 0, 0);
      __builtin_amdgcn_s_setprio(0);
    }
  };

  // prologue: tile 0 -> buf 0
  issueA(0);
  issueB(0, 0);
  writeA(0);
  asm volatile("s_waitcnt vmcnt(0) lgkmcnt(0)" ::: "memory");
  __builtin_amdgcn_s_barrier();
  __builtin_amdgcn_sched_barrier(0);

  int buf = 0;
  for (int t = 0; t < NT; ++t) {
    const int tn = (t + 1 < NT) ? t + 1 : t;   // last iter re-stages (L2-hot)
    issueA(tn);          // 2 A loads first (older in FIFO)
    issueB(buf ^ 1, tn); // 4 B async16 after
    compute(buf);        // ~1200cy of MFMA per SIMD hides the A latency
    writeA(buf ^ 1);     // counted vmcnt(4): A retired, B still in flight
    asm volatile("s_waitcnt vmcnt(0) lgkmcnt(0)" ::: "memory"); // B issued ~1 compute ago
    __builtin_amdgcn_s_barrier();
    __builtin_amdgcn_sched_barrier(0);
    buf ^= 1;
  }

  // ---- epilogue: C/D frag map col = lane&15, row = (lane>>4)*4 + reg ----
  const int colc = lane & 15;
  const int rowb = (lane >> 4) * 4;
  if (CT) {
    // per-wave LDS transpose -> 128B-coalesced stores of C^T[n][m]
    __bf16* T = (__bf16*)smem + wid * 1152;     // 16 x 72 per wave
    const int mbase = mt * 128 + wm * 64;
#pragma unroll
    for (int ni = 0; ni < 8; ++ni) {
#pragma unroll
      for (int mi = 0; mi < 4; ++mi)
#pragma unroll
        for (int r = 0; r < 4; ++r)
          T[colc * 72 + mi * 16 + rowb + r] = (__bf16)acc[mi][ni][r];
      __bf16* outp = Co + (size_t)batch * BT_DIM * M
                        + (size_t)(wn * 128 + ni * 16) * M + mbase + lane;
#pragma unroll
      for (int r16 = 0; r16 < 16; ++r16)
        outp[(size_t)r16 * M] = T[r16 * 72 + lane];
    }
  } else {
#pragma unroll
    for (int mi = 0; mi < 4; ++mi) {
#pragma unroll
      for (int ni = 0; ni < 8; ++ni) {
        const int m = mt * 128 + wm * 64 + mi * 16 + rowb;
        const int n = wn * 128 + ni * 16 + colc;
#pragma unroll
        for (int r = 0; r < 4; ++r)
          Co[((size_t)batch * M + m + r) * BT_DIM + n] = (__bf16)acc[mi][ni][r];
      }
    }
  }
}

// ---------------------------------------------------------------------------
// Kernel 3: channel mix 8->32 + squared ReLU.
// ---------------------------------------------------------------------------
__global__ void mix1_kernel(const __bf16* __restrict__ Y1,
                            const float* __restrict__ dw1,
                            __bf16* __restrict__ h2) {
  const int gidx = blockIdx.x * 256 + threadIdx.x;
  const int g8 = gidx & 511, bt = gidx >> 9;
  const int g0 = g8 * 8;

  float y[C_DIM][8];
#pragma unroll
  for (int c = 0; c < C_DIM; ++c) {
    bf16x8 v = *(const bf16x8*)(Y1 + ((size_t)c * BT_DIM + bt) * FH_DIM + g0);
#pragma unroll
    for (int j = 0; j < 8; ++j) y[c][j] = (float)v[j];
  }
  for (int d = 0; d < CH_DIM; ++d) {
    float s[8] = {0.f,0.f,0.f,0.f,0.f,0.f,0.f,0.f};
#pragma unroll
    for (int c = 0; c < C_DIM; ++c) {
      const float wv = dw1[d * C_DIM + c];
#pragma unroll
      for (int j = 0; j < 8; ++j) s[j] += wv * y[c][j];
    }
    bf16x8 o;
#pragma unroll
    for (int j = 0; j < 8; ++j) {
      float r = s[j] > 0.f ? s[j] : 0.f;
      o[j] = (__bf16)(r * r);
    }
    *(bf16x8*)(h2 + ((size_t)d * BT_DIM + bt) * FH_DIM + g0) = o;
  }
}

// ---------------------------------------------------------------------------
// Kernel 4: channel mix 32->8 + residual.
// ---------------------------------------------------------------------------
__global__ void mix2_kernel(const float* __restrict__ x,
                            const __bf16* __restrict__ Y2,
                            const float* __restrict__ dw2,
                            float* __restrict__ out) {
  const int gidx = blockIdx.x * 256 + threadIdx.x;
  const int t4 = gidx & 63;
  const int f  = (gidx >> 6) & 1023;
  const int dd = (gidx >> 16) & 7;
  const int b  = gidx >> 19;
  const int t0 = t4 * 4;

  const size_t oidx = ((size_t)(b * C_DIM + dd) * F_DIM + f) * T_DIM + t0;
  float4 acc = *(const float4*)(x + oidx);
  for (int d = 0; d < CH_DIM; ++d) {
    const float wv = dw2[dd * CH_DIM + d];
    bf16x4 v = *(const bf16x4*)(Y2 + ((size_t)d * F_DIM + f) * BT_DIM + b * T_DIM + t0);
    acc.x += wv * (float)v[0];
    acc.y += wv * (float)v[1];
    acc.z += wv * (float)v[2];
    acc.w += wv * (float)v[3];
  }
  *(float4*)(out + oidx) = acc;
}

// ---------------------------------------------------------------------------
extern "C" void kernel_launch(void* const* d_in, const int* in_sizes, int n_in,
                              void* d_out, int out_size, void* d_ws, size_t ws_size,
                              hipStream_t stream) {
  const float* x   = (const float*)d_in[0];
  const float* lnw = (const float*)d_in[1];
  const float* lnb = (const float*)d_in[2];
  const float* pw1 = (const float*)d_in[3];
  const float* dw1 = (const float*)d_in[4];
  const float* pw2 = (const float*)d_in[5];
  const float* dw2 = (const float*)d_in[6];
  float* out = (float*)d_out;

  char* ws = (char*)d_ws;
  __bf16* hn = (__bf16*)(ws);                    // [C][512][F]    8 MB
  __bf16* Y1 = (__bf16*)(ws + (8ULL << 20));     // [C][512][Fh]  32 MB
  __bf16* h2 = (__bf16*)(ws + (40ULL << 20));    // [Ch][512][Fh] 128 MB
  __bf16* Y2 = (__bf16*)(ws);                    // [Ch][F][512]  32 MB (reuse)

  (void)hipFuncSetAttribute((const void*)gemm_bn512<5, true>,
                            hipFuncAttributeMaxDynamicSharedMemorySize, 81920);
  (void)hipFuncSetAttribute((const void*)gemm_bn512<3, false>,
                            hipFuncAttributeMaxDynamicSharedMemorySize, 81920);

  ln_kernel<<<dim3(T_DIM / 16, C_DIM, B_DIM), 256, 0, stream>>>(x, lnw, lnb, hn);
  // pw1: per c: [4096 x 1024] @ [1024 x 512]^T -> Y1^T [512][4096]
  gemm_bn512<5, true><<<256, 512, 81920, stream>>>(pw1, hn, Y1, FH_DIM, F_DIM);
  mix1_kernel<<<(BT_DIM * (FH_DIM / 8)) / 256, 256, 0, stream>>>(Y1, dw1, h2);
  // pw2: per d: [1024 x 4096] @ [4096 x 512]^T -> Y2 [1024][512]
  gemm_bn512<3, false><<<256, 512, 81920, stream>>>(pw2, h2, Y2, F_DIM, FH_DIM);
  mix2_kernel<<<(B_DIM * C_DIM * F_DIM * (T_DIM / 4)) / 256, 256, 0, stream>>>(x, Y2, dw2, out);
}

// Round 10
// 333.335 us; speedup vs baseline: 1.9931x; 1.1675x over previous
//
#include <hip/hip_runtime.h>

// Problem dims (fixed)
#define B_DIM  2
#define C_DIM  8
#define F_DIM  1024
#define T_DIM  256
#define CH_DIM 32
#define FH_DIM 4096
#define BT_DIM 512   // B*T

typedef __bf16 bf16x8 __attribute__((ext_vector_type(8)));
typedef __bf16 bf16x4 __attribute__((ext_vector_type(4)));
typedef float  f32x4  __attribute__((ext_vector_type(4)));

__device__ __forceinline__ void async16(const void* g, void* l) {
  __builtin_amdgcn_global_load_lds(
      (const __attribute__((address_space(1))) unsigned int*)g,
      (__attribute__((address_space(3))) unsigned int*)l, 16, 0, 0);
}

#define LGKM0_SCHED() do { \
    asm volatile("s_waitcnt lgkmcnt(0)" ::: "memory"); \
    __builtin_amdgcn_sched_barrier(0); } while (0)

// ---------------------------------------------------------------------------
// Kernel 1: LayerNorm over F (per b,c,t) + affine, written TRANSPOSED:
//   hn[c][b*T + t][f]  (bf16)   (unchanged, proven)
// ---------------------------------------------------------------------------
__global__ void ln_kernel(const float* __restrict__ x,
                          const float* __restrict__ lnw,
                          const float* __restrict__ lnb,
                          __bf16* __restrict__ hn) {
  const int tb = blockIdx.x;      // t-chunk of 16
  const int c  = blockIdx.y;
  const int b  = blockIdx.z;
  const int tid = threadIdx.x;
  const int tx = tid & 15, ty = tid >> 4;
  const int t0 = tb * 16;

  const float* xp = x + (size_t)(b * C_DIM + c) * F_DIM * T_DIM;

  float s = 0.f, s2 = 0.f;
  for (int f = ty; f < F_DIM; f += 16) {
    float v = xp[f * T_DIM + t0 + tx];
    s += v; s2 += v * v;
  }
  __shared__ float ps[16][16], ps2[16][16];
  __shared__ float mean_s[16], rstd_s[16];
  ps[ty][tx] = s; ps2[ty][tx] = s2;
  __syncthreads();
  if (tid < 16) {
    float a = 0.f, a2 = 0.f;
    for (int j = 0; j < 16; ++j) { a += ps[j][tid]; a2 += ps2[j][tid]; }
    float mu  = a * (1.0f / F_DIM);
    float var = a2 * (1.0f / F_DIM) - mu * mu;
    mean_s[tid] = mu;
    rstd_s[tid] = rsqrtf(var + 1e-8f);
  }
  __syncthreads();

  __shared__ float tile[64][17];
  __bf16* hp = hn + ((size_t)c * BT_DIM + b * T_DIM + t0) * F_DIM;
  for (int ff = 0; ff < 16; ++ff) {
    const int f0 = ff * 64;
#pragma unroll
    for (int it = 0; it < 4; ++it) {
      int e  = it * 256 + tid;
      int fi = e >> 4, ti = e & 15;
      float v = xp[(f0 + fi) * T_DIM + t0 + ti];
      v = (v - mean_s[ti]) * rstd_s[ti];
      v = v * lnw[c * F_DIM + f0 + fi] + lnb[c * F_DIM + f0 + fi];
      tile[fi][ti] = v;
    }
    __syncthreads();
#pragma unroll
    for (int it = 0; it < 4; ++it) {
      int e  = it * 256 + tid;
      int fx = e & 63, tw = e >> 6;
      hp[(size_t)tw * F_DIM + f0 + fx] = (__bf16)tile[fx][tw];
    }
    __syncthreads();
  }
}

// ---------------------------------------------------------------------------
// Kernel 2a (pw1): UNCHANGED from R8 (gemm_bn512<5,true>, passed twice).
// ---------------------------------------------------------------------------
template<int MTBITS, bool CT>
__global__ __launch_bounds__(512, 2)
void gemm_bn512(const float* __restrict__ A, const __bf16* __restrict__ Bm,
                __bf16* __restrict__ Co, const int M, const int K) {
  const int bid = blockIdx.x;
  const int xcd = bid & 7, idx = bid >> 3;
  const int batch = xcd * (32 >> MTBITS) + (idx >> MTBITS);
  const int mt    = idx & ((1 << MTBITS) - 1);

  const int tid = threadIdx.x, lane = tid & 63, wid = tid >> 6;

  const float*  Ab = A  + (size_t)batch * M * K + (size_t)(mt * 128) * K;
  const __bf16* Bb = Bm + (size_t)batch * BT_DIM * K;

  extern __shared__ __align__(16) char smem[];
  __bf16* const AS = (__bf16*)smem;
  __bf16* const BS = (__bf16*)(smem + 16384);

  const int a_r = tid >> 2, a_q = tid & 3;
  const int a_swz = a_q ^ ((a_r >> 1) & 3);
  const float* const aBase = Ab + (size_t)a_r * K + a_q * 8;

  const int b_r0 = wid * 64 + (lane >> 2);
  const int b_s  = (lane & 3) ^ ((lane >> 3) & 3);

  const int wm = wid >> 2, wn = wid & 3;
  const int lr = lane & 15, khi = lane >> 4;
  const int rsw = (lr >> 1) & 3;

  f32x4 acc[4][8] = {};
  float4 sa[2];
  const int NT = K >> 5;

  auto issueA = [&](int tt) {
    sa[0] = *(const float4*)(aBase + (size_t)tt * 32);
    sa[1] = *(const float4*)(aBase + (size_t)tt * 32 + 4);
  };
  auto writeA = [&](int buf) {
    bf16x8 v;
    v[0]=(__bf16)sa[0].x; v[1]=(__bf16)sa[0].y; v[2]=(__bf16)sa[0].z; v[3]=(__bf16)sa[0].w;
    v[4]=(__bf16)sa[1].x; v[5]=(__bf16)sa[1].y; v[6]=(__bf16)sa[1].z; v[7]=(__bf16)sa[1].w;
    *(bf16x8*)(AS + buf * 4096 + a_r * 32 + a_swz * 8) = v;
  };
  auto issueB = [&](int buf, int tt) {
#pragma unroll
    for (int j = 0; j < 4; ++j) {
      const int r = b_r0 + j * 16;
      async16(Bb + (size_t)r * K + (size_t)tt * 32 + b_s * 8,
              BS + buf * 16384 + (wid * 64 + j * 16) * 32);
    }
  };
  auto compute = [&](int buf) {
    const __bf16* As = AS + buf * 4096;
    const __bf16* Bs = BS + buf * 16384;
    const int so = (khi ^ rsw) << 3;
    bf16x8 af[4];
#pragma unroll
    for (int mi = 0; mi < 4; ++mi)
      af[mi] = *(const bf16x8*)(As + (wm * 64 + mi * 16 + lr) * 32 + so);
#pragma unroll
    for (int h = 0; h < 2; ++h) {
      bf16x8 bq[4];
#pragma unroll
      for (int nj = 0; nj < 4; ++nj)
        bq[nj] = *(const bf16x8*)(Bs + (wn * 128 + (h * 4 + nj) * 16 + lr) * 32 + so);
      __builtin_amdgcn_s_setprio(1);
#pragma unroll
      for (int mi = 0; mi < 4; ++mi)
#pragma unroll
        for (int nj = 0; nj < 4; ++nj)
          acc[mi][h * 4 + nj] =
              __builtin_amdgcn_mfma_f32_16x16x32_bf16(af[mi], bq[nj], acc[mi][h * 4 + nj], 0, 0, 0);
      __builtin_amdgcn_s_setprio(0);
    }
  };

  issueA(0);
  issueB(0, 0);
  writeA(0);
  asm volatile("s_waitcnt vmcnt(0) lgkmcnt(0)" ::: "memory");
  __builtin_amdgcn_s_barrier();
  __builtin_amdgcn_sched_barrier(0);

  int buf = 0;
  for (int t = 0; t < NT; ++t) {
    const int tn = (t + 1 < NT) ? t + 1 : t;
    issueA(tn);
    issueB(buf ^ 1, tn);
    compute(buf);
    writeA(buf ^ 1);
    asm volatile("s_waitcnt vmcnt(0) lgkmcnt(0)" ::: "memory");
    __builtin_amdgcn_s_barrier();
    __builtin_amdgcn_sched_barrier(0);
    buf ^= 1;
  }

  const int colc = lane & 15;
  const int rowb = (lane >> 4) * 4;
  if (CT) {
    __bf16* T = (__bf16*)smem + wid * 1152;
    const int mbase = mt * 128 + wm * 64;
#pragma unroll
    for (int ni = 0; ni < 8; ++ni) {
#pragma unroll
      for (int mi = 0; mi < 4; ++mi)
#pragma unroll
        for (int r = 0; r < 4; ++r)
          T[colc * 72 + mi * 16 + rowb + r] = (__bf16)acc[mi][ni][r];
      __bf16* outp = Co + (size_t)batch * BT_DIM * M
                        + (size_t)(wn * 128 + ni * 16) * M + mbase + lane;
#pragma unroll
      for (int r16 = 0; r16 < 16; ++r16)
        outp[(size_t)r16 * M] = T[r16 * 72 + lane];
    }
  } else {
#pragma unroll
    for (int mi = 0; mi < 4; ++mi) {
#pragma unroll
      for (int ni = 0; ni < 8; ++ni) {
        const int m = mt * 128 + wm * 64 + mi * 16 + rowb;
        const int n = wn * 128 + ni * 16 + colc;
#pragma unroll
        for (int r = 0; r < 4; ++r)
          Co[((size_t)batch * M + m + r) * BT_DIM + n] = (__bf16)acc[mi][ni][r];
      }
    }
  }
}

// ---------------------------------------------------------------------------
// Kernel 2b (pw2): 8-phase counted-vmcnt pipeline, distance-2 A prefetch.
// BM=256 x BN=256, BK=64, 512 thr (8 waves 2Mx4N, wave tile 128x64).
// LDS 160KB: A dbuf 2x32KB + B ring 3x32KB.
// sa regs hold A(t+1) (loaded LAST iter). p4-p7: writeA2(A(t+1)) then
// issueA2(A(t+2)) (WAR-safe). Every compiler counted wait targets loads a
// full iteration old; B prefetches are never retired early (A loads are
// older in FIFO); boundary has NO vmcnt. Never drains.
// Grid 256 (1/CU): batch = xcd*4 + idx>>3 (B panel L2-local per XCD).
// ---------------------------------------------------------------------------
__global__ __launch_bounds__(512, 2)
void gemm_pw2_8p(const float* __restrict__ A, const __bf16* __restrict__ Bm,
                 __bf16* __restrict__ Co) {
  const int M = F_DIM, K = FH_DIM;
  const int NT = K >> 6;                       // 64 K-tiles
  const int bid = blockIdx.x;
  const int xcd = bid & 7, idx = bid >> 3;     // idx 0..31
  const int batch = xcd * 4 + (idx >> 3);      // 32 batches, 4/XCD
  const int tile  = idx & 7;
  const int mt = tile >> 1, nt = tile & 1;     // 4 mt x 2 nt

  const int tid = threadIdx.x, lane = tid & 63, wid = tid >> 6;

  const float*  Ab = A  + (size_t)batch * M * K + (size_t)(mt * 256) * K;
  const __bf16* Bb = Bm + (size_t)batch * BT_DIM * K + (size_t)(nt * 256) * K;

  extern __shared__ __align__(16) char smem[];
  __bf16* const AS = (__bf16*)smem;            // 2 x 16384 elems (32KB)
  __bf16* const BS = (__bf16*)(smem + 65536);  // 3 x 16384 elems (32KB)

  const int wm = wid >> 2, wn = wid & 3;       // wave tile 128x64
  const int lr = lane & 15, khi = lane >> 4;
  const int lsw = lr & 7;

  const int b_row = lane >> 3;                 // row within 8-row chunk
  const int b_src = (lane & 7) ^ b_row;        // pre-swizzled 16B source slot

  f32x4 acc[8][4] = {};
  float4 sa[8];
  bf16x8 af[4];

  auto issueB1 = [&](int sbuf, int tt, int j) {
    const int chunk = j * 8 + wid;
    async16(Bb + (size_t)(chunk * 8 + b_row) * K + (size_t)tt * 64 + b_src * 8,
            BS + sbuf * 16384 + chunk * 512);
  };
  auto issueA2 = [&](int tt, int i0) {
#pragma unroll
    for (int i = i0; i < i0 + 2; ++i) {
      const int c = i * 512 + tid;
      sa[i] = *(const float4*)(Ab + (size_t)(c >> 4) * K + (size_t)tt * 64 + (c & 15) * 4);
    }
  };
  auto writeA2 = [&](int abuf, int i0) {
#pragma unroll
    for (int i = i0; i < i0 + 2; ++i) {
      const int c = i * 512 + tid;
      const int r = c >> 4;
      const int s = ((c & 15) >> 1) ^ (r & 7);
      bf16x4 v;
      v[0]=(__bf16)sa[i].x; v[1]=(__bf16)sa[i].y; v[2]=(__bf16)sa[i].z; v[3]=(__bf16)sa[i].w;
      *(bf16x4*)(AS + abuf * 16384 + r * 64 + s * 8 + (c & 1) * 4) = v;
    }
  };
  auto readA = [&](int abuf, int mq, int ks) {
#pragma unroll
    for (int j = 0; j < 4; ++j) {
      const int row = wm * 128 + (mq * 4 + j) * 16 + lr;
      af[j] = *(const bf16x8*)(AS + abuf * 16384 + row * 64 + (((ks << 2) | khi) ^ lsw) * 8);
    }
  };
  auto readB2 = [&](bf16x8* bq, int rbuf, int np, int ks) {
#pragma unroll
    for (int j = 0; j < 2; ++j) {
      const int row = wn * 64 + (np * 2 + j) * 16 + lr;
      bq[j] = *(const bf16x8*)(BS + rbuf * 16384 + row * 64 + (((ks << 2) | khi) ^ lsw) * 8);
    }
  };
  auto mfma8 = [&](const bf16x8* bq, int mq, int np) {
    __builtin_amdgcn_s_setprio(1);
#pragma unroll
    for (int j = 0; j < 4; ++j)
#pragma unroll
      for (int n = 0; n < 2; ++n)
        acc[mq * 4 + j][np * 2 + n] =
            __builtin_amdgcn_mfma_f32_16x16x32_bf16(af[j], bq[n], acc[mq * 4 + j][np * 2 + n], 0, 0, 0);
    __builtin_amdgcn_s_setprio(0);
  };

  // ---- prologue: A(0)->AS[0]; A(1)->sa; B(0)->BS[0]; B(1)->BS[1] ----
  issueA2(0, 0); issueA2(0, 2); issueA2(0, 4); issueA2(0, 6);
  issueB1(0, 0, 0); issueB1(0, 0, 1); issueB1(0, 0, 2); issueB1(0, 0, 3);
  issueB1(1, 1, 0); issueB1(1, 1, 1); issueB1(1, 1, 2); issueB1(1, 1, 3);
  writeA2(0, 0); writeA2(0, 2); writeA2(0, 4); writeA2(0, 6);  // waits A(0) only
  issueA2(1, 0); issueA2(1, 2); issueA2(1, 4); issueA2(1, 6);  // A(1) -> sa
  asm volatile("s_waitcnt vmcnt(12)" ::: "memory");  // B(0) landed; B(1)+A(1) in flight
  LGKM0_SCHED();
  __builtin_amdgcn_s_barrier();

  int cur = 0;
  for (int t = 0; t < NT; ++t) {
    const int rd = t % 3, st = (t + 2) % 3;
    const int tN = (t + 2 < NT) ? t + 2 : NT - 1;
    bf16x8 bq[2];
    // p0
    issueB1(st, tN, 0);
    readA(cur, 0, 0); readB2(bq, rd, 0, 0);
    __builtin_amdgcn_s_barrier(); LGKM0_SCHED();
    mfma8(bq, 0, 0); __builtin_amdgcn_s_barrier();
    // p1
    issueB1(st, tN, 1);
    readB2(bq, rd, 1, 0);
    __builtin_amdgcn_s_barrier(); LGKM0_SCHED();
    mfma8(bq, 0, 1); __builtin_amdgcn_s_barrier();
    // p2
    issueB1(st, tN, 2);
    readA(cur, 1, 0); readB2(bq, rd, 0, 0);
    __builtin_amdgcn_s_barrier(); LGKM0_SCHED();
    mfma8(bq, 1, 0); __builtin_amdgcn_s_barrier();
    // p3
    issueB1(st, tN, 3);
    readB2(bq, rd, 1, 0);
    __builtin_amdgcn_s_barrier(); LGKM0_SCHED();
    mfma8(bq, 1, 1); __builtin_amdgcn_s_barrier();
    // p4  (write A(t+1) half0, then prefetch A(t+2) half0 into freed regs)
    writeA2(cur ^ 1, 0); issueA2(tN, 0);
    readA(cur, 0, 1); readB2(bq, rd, 0, 1);
    __builtin_amdgcn_s_barrier(); LGKM0_SCHED();
    mfma8(bq, 0, 0); __builtin_amdgcn_s_barrier();
    // p5
    writeA2(cur ^ 1, 2); issueA2(tN, 2);
    readB2(bq, rd, 1, 1);
    __builtin_amdgcn_s_barrier(); LGKM0_SCHED();
    mfma8(bq, 0, 1); __builtin_amdgcn_s_barrier();
    // p6
    writeA2(cur ^ 1, 4); issueA2(tN, 4);
    readA(cur, 1, 1); readB2(bq, rd, 0, 1);
    __builtin_amdgcn_s_barrier(); LGKM0_SCHED();
    mfma8(bq, 1, 0); __builtin_amdgcn_s_barrier();
    // p7
    writeA2(cur ^ 1, 6); issueA2(tN, 6);
    readB2(bq, rd, 1, 1);
    __builtin_amdgcn_s_barrier(); LGKM0_SCHED();
    mfma8(bq, 1, 1);
    // boundary: NO vmcnt — B(t+2)+A(t+2) stay in flight across the barrier
    __builtin_amdgcn_s_barrier();
    cur ^= 1;
  }

  // ---- epilogue: C/D map col = lane&15, row = (lane>>4)*4 + reg ----
  const int colc = lane & 15;
  const int rowb = (lane >> 4) * 4;
#pragma unroll
  for (int mi = 0; mi < 8; ++mi) {
#pragma unroll
    for (int ni = 0; ni < 4; ++ni) {
      const int m = mt * 256 + wm * 128 + mi * 16 + rowb;
      const int n = nt * 256 + wn * 64 + ni * 16 + colc;
#pragma unroll
      for (int r = 0; r < 4; ++r)
        Co[((size_t)batch * M + m + r) * BT_DIM + n] = (__bf16)acc[mi][ni][r];
    }
  }
}

// ---------------------------------------------------------------------------
// Kernel 3: channel mix 8->32 + squared ReLU. (unchanged)
// ---------------------------------------------------------------------------
__global__ void mix1_kernel(const __bf16* __restrict__ Y1,
                            const float* __restrict__ dw1,
                            __bf16* __restrict__ h2) {
  const int gidx = blockIdx.x * 256 + threadIdx.x;
  const int g8 = gidx & 511, bt = gidx >> 9;
  const int g0 = g8 * 8;

  float y[C_DIM][8];
#pragma unroll
  for (int c = 0; c < C_DIM; ++c) {
    bf16x8 v = *(const bf16x8*)(Y1 + ((size_t)c * BT_DIM + bt) * FH_DIM + g0);
#pragma unroll
    for (int j = 0; j < 8; ++j) y[c][j] = (float)v[j];
  }
  for (int d = 0; d < CH_DIM; ++d) {
    float s[8] = {0.f,0.f,0.f,0.f,0.f,0.f,0.f,0.f};
#pragma unroll
    for (int c = 0; c < C_DIM; ++c) {
      const float wv = dw1[d * C_DIM + c];
#pragma unroll
      for (int j = 0; j < 8; ++j) s[j] += wv * y[c][j];
    }
    bf16x8 o;
#pragma unroll
    for (int j = 0; j < 8; ++j) {
      float r = s[j] > 0.f ? s[j] : 0.f;
      o[j] = (__bf16)(r * r);
    }
    *(bf16x8*)(h2 + ((size_t)d * BT_DIM + bt) * FH_DIM + g0) = o;
  }
}

// ---------------------------------------------------------------------------
// Kernel 4: channel mix 32->8 + residual. Y2 read once per element.
// 512 blocks x 256 threads = 131072 threads (b x f x t4 = 2x1024x64).
// ---------------------------------------------------------------------------
__global__ void mix2_kernel(const float* __restrict__ x,
                            const __bf16* __restrict__ Y2,
                            const float* __restrict__ dw2,
                            float* __restrict__ out) {
  const int gidx = blockIdx.x * 256 + threadIdx.x;   // < 131072
  const int t4 = gidx & 63;
  const int f  = (gidx >> 6) & 1023;
  const int b  = gidx >> 16;                         // 0..1
  const int t0 = t4 * 4;

  float4 r[C_DIM];
#pragma unroll
  for (int dd = 0; dd < C_DIM; ++dd)
    r[dd] = *(const float4*)(x + ((size_t)(b * C_DIM + dd) * F_DIM + f) * T_DIM + t0);

  for (int d = 0; d < CH_DIM; ++d) {
    bf16x4 v = *(const bf16x4*)(Y2 + ((size_t)d * F_DIM + f) * BT_DIM + b * T_DIM + t0);
    const float v0 = (float)v[0], v1 = (float)v[1], v2 = (float)v[2], v3 = (float)v[3];
#pragma unroll
    for (int dd = 0; dd < C_DIM; ++dd) {
      const float w = dw2[dd * CH_DIM + d];
      r[dd].x += w * v0; r[dd].y += w * v1; r[dd].z += w * v2; r[dd].w += w * v3;
    }
  }
#pragma unroll
  for (int dd = 0; dd < C_DIM; ++dd)
    *(float4*)(out + ((size_t)(b * C_DIM + dd) * F_DIM + f) * T_DIM + t0) = r[dd];
}

// ---------------------------------------------------------------------------
extern "C" void kernel_launch(void* const* d_in, const int* in_sizes, int n_in,
                              void* d_out, int out_size, void* d_ws, size_t ws_size,
                              hipStream_t stream) {
  const float* x   = (const float*)d_in[0];
  const float* lnw = (const float*)d_in[1];
  const float* lnb = (const float*)d_in[2];
  const float* pw1 = (const float*)d_in[3];
  const float* dw1 = (const float*)d_in[4];
  const float* pw2 = (const float*)d_in[5];
  const float* dw2 = (const float*)d_in[6];
  float* out = (float*)d_out;

  char* ws = (char*)d_ws;
  __bf16* hn = (__bf16*)(ws);                    // [C][512][F]    8 MB
  __bf16* Y1 = (__bf16*)(ws + (8ULL << 20));     // [C][512][Fh]  32 MB
  __bf16* h2 = (__bf16*)(ws + (40ULL << 20));    // [Ch][512][Fh] 128 MB
  __bf16* Y2 = (__bf16*)(ws);                    // [Ch][F][512]  32 MB (reuse)

  (void)hipFuncSetAttribute((const void*)gemm_bn512<5, true>,
                            hipFuncAttributeMaxDynamicSharedMemorySize, 81920);
  (void)hipFuncSetAttribute((const void*)gemm_pw2_8p,
                            hipFuncAttributeMaxDynamicSharedMemorySize, 163840);

  ln_kernel<<<dim3(T_DIM / 16, C_DIM, B_DIM), 256, 0, stream>>>(x, lnw, lnb, hn);
  // pw1: per c: [4096 x 1024] @ [1024 x 512]^T -> Y1^T [512][4096]
  gemm_bn512<5, true><<<256, 512, 81920, stream>>>(pw1, hn, Y1, FH_DIM, F_DIM);
  mix1_kernel<<<(BT_DIM * (FH_DIM / 8)) / 256, 256, 0, stream>>>(Y1, dw1, h2);
  // pw2: per d: [1024 x 4096] @ [4096 x 512]^T -> Y2 [1024][512]
  gemm_pw2_8p<<<256, 512, 163840, stream>>>(pw2, h2, Y2);
  mix2_kernel<<<512, 256, 0, stream>>>(x, Y2, dw2, out);
}

// Round 11
// 316.693 us; speedup vs baseline: 2.0978x; 1.0525x over previous
//
#include <hip/hip_runtime.h>

// Problem dims (fixed)
#define B_DIM  2
#define C_DIM  8
#define F_DIM  1024
#define T_DIM  256
#define CH_DIM 32
#define FH_DIM 4096
#define BT_DIM 512   // B*T

typedef __bf16 bf16x8 __attribute__((ext_vector_type(8)));
typedef __bf16 bf16x4 __attribute__((ext_vector_type(4)));
typedef float  f32x4  __attribute__((ext_vector_type(4)));

__device__ __forceinline__ void async16(const void* g, void* l) {
  __builtin_amdgcn_global_load_lds(
      (const __attribute__((address_space(1))) unsigned int*)g,
      (__attribute__((address_space(3))) unsigned int*)l, 16, 0, 0);
}

#define LGKM0_SCHED() do { \
    asm volatile("s_waitcnt lgkmcnt(0)" ::: "memory"); \
    __builtin_amdgcn_sched_barrier(0); } while (0)

// ---------------------------------------------------------------------------
// Kernel 1: LayerNorm over F (per b,c,t) + affine, written TRANSPOSED:
//   hn[c][b*T + t][f]  (bf16)   (unchanged, proven)
// ---------------------------------------------------------------------------
__global__ void ln_kernel(const float* __restrict__ x,
                          const float* __restrict__ lnw,
                          const float* __restrict__ lnb,
                          __bf16* __restrict__ hn) {
  const int tb = blockIdx.x;      // t-chunk of 16
  const int c  = blockIdx.y;
  const int b  = blockIdx.z;
  const int tid = threadIdx.x;
  const int tx = tid & 15, ty = tid >> 4;
  const int t0 = tb * 16;

  const float* xp = x + (size_t)(b * C_DIM + c) * F_DIM * T_DIM;

  float s = 0.f, s2 = 0.f;
  for (int f = ty; f < F_DIM; f += 16) {
    float v = xp[f * T_DIM + t0 + tx];
    s += v; s2 += v * v;
  }
  __shared__ float ps[16][16], ps2[16][16];
  __shared__ float mean_s[16], rstd_s[16];
  ps[ty][tx] = s; ps2[ty][tx] = s2;
  __syncthreads();
  if (tid < 16) {
    float a = 0.f, a2 = 0.f;
    for (int j = 0; j < 16; ++j) { a += ps[j][tid]; a2 += ps2[j][tid]; }
    float mu  = a * (1.0f / F_DIM);
    float var = a2 * (1.0f / F_DIM) - mu * mu;
    mean_s[tid] = mu;
    rstd_s[tid] = rsqrtf(var + 1e-8f);
  }
  __syncthreads();

  __shared__ float tile[64][17];
  __bf16* hp = hn + ((size_t)c * BT_DIM + b * T_DIM + t0) * F_DIM;
  for (int ff = 0; ff < 16; ++ff) {
    const int f0 = ff * 64;
#pragma unroll
    for (int it = 0; it < 4; ++it) {
      int e  = it * 256 + tid;
      int fi = e >> 4, ti = e & 15;
      float v = xp[(f0 + fi) * T_DIM + t0 + ti];
      v = (v - mean_s[ti]) * rstd_s[ti];
      v = v * lnw[c * F_DIM + f0 + fi] + lnb[c * F_DIM + f0 + fi];
      tile[fi][ti] = v;
    }
    __syncthreads();
#pragma unroll
    for (int it = 0; it < 4; ++it) {
      int e  = it * 256 + tid;
      int fx = e & 63, tw = e >> 6;
      hp[(size_t)tw * F_DIM + f0 + fx] = (__bf16)tile[fx][tw];
    }
    __syncthreads();
  }
}

// ---------------------------------------------------------------------------
// Kernel 2: 8-phase counted-vmcnt GEMM (R10-proven structure, now shared).
// BM=256 x BN=256, BK=64, 512 thr (8 waves 2Mx4N, wave tile 128x64).
// LDS 160KB: A dbuf 2x32KB + B ring 3x32KB. Distance-2 A reg-prefetch;
// boundary has NO vmcnt (B(t+2)+A(t+2) stay in flight). Never drains.
//   C[m][n] = sum_k A[batch][m][k] * Bt[batch][n][k]
// Grid 256 (1/CU): batch = xcd*(32>>TPB) + idx>>TPB (B panel L2-local/XCD).
// TPB_BITS: tiles/batch = 1<<TPB (mt = tile>>1, nt = tile&1).
// CT=false: scatter store C[m][n].  CT=true: per-wave LDS-transpose epilogue
// (two 64-row halves), 128B-coalesced stores of C^T[n][m].
// ---------------------------------------------------------------------------
template<int TPB_BITS, bool CT>
__global__ __launch_bounds__(512, 2)
void gemm_8p(const float* __restrict__ A, const __bf16* __restrict__ Bm,
             __bf16* __restrict__ Co, const int M, const int K) {
  const int NT = K >> 6;
  const int bid = blockIdx.x;
  const int xcd = bid & 7, idx = bid >> 3;     // idx 0..31
  const int batch = xcd * (32 >> TPB_BITS) + (idx >> TPB_BITS);
  const int tile  = idx & ((1 << TPB_BITS) - 1);
  const int mt = tile >> 1, nt = tile & 1;

  const int tid = threadIdx.x, lane = tid & 63, wid = tid >> 6;

  const float*  Ab = A  + (size_t)batch * M * K + (size_t)(mt * 256) * K;
  const __bf16* Bb = Bm + (size_t)batch * BT_DIM * K + (size_t)(nt * 256) * K;

  extern __shared__ __align__(16) char smem[];
  __bf16* const AS = (__bf16*)smem;            // 2 x 16384 elems (32KB)
  __bf16* const BS = (__bf16*)(smem + 65536);  // 3 x 16384 elems (32KB)

  const int wm = wid >> 2, wn = wid & 3;       // wave tile 128x64
  const int lr = lane & 15, khi = lane >> 4;
  const int lsw = lr & 7;

  const int b_row = lane >> 3;                 // row within 8-row chunk
  const int b_src = (lane & 7) ^ b_row;        // pre-swizzled 16B source slot

  f32x4 acc[8][4] = {};
  float4 sa[8];
  bf16x8 af[4];

  auto issueB1 = [&](int sbuf, int tt, int j) {
    const int chunk = j * 8 + wid;
    async16(Bb + (size_t)(chunk * 8 + b_row) * K + (size_t)tt * 64 + b_src * 8,
            BS + sbuf * 16384 + chunk * 512);
  };
  auto issueA2 = [&](int tt, int i0) {
#pragma unroll
    for (int i = i0; i < i0 + 2; ++i) {
      const int c = i * 512 + tid;
      sa[i] = *(const float4*)(Ab + (size_t)(c >> 4) * K + (size_t)tt * 64 + (c & 15) * 4);
    }
  };
  auto writeA2 = [&](int abuf, int i0) {
#pragma unroll
    for (int i = i0; i < i0 + 2; ++i) {
      const int c = i * 512 + tid;
      const int r = c >> 4;
      const int s = ((c & 15) >> 1) ^ (r & 7);
      bf16x4 v;
      v[0]=(__bf16)sa[i].x; v[1]=(__bf16)sa[i].y; v[2]=(__bf16)sa[i].z; v[3]=(__bf16)sa[i].w;
      *(bf16x4*)(AS + abuf * 16384 + r * 64 + s * 8 + (c & 1) * 4) = v;
    }
  };
  auto readA = [&](int abuf, int mq, int ks) {
#pragma unroll
    for (int j = 0; j < 4; ++j) {
      const int row = wm * 128 + (mq * 4 + j) * 16 + lr;
      af[j] = *(const bf16x8*)(AS + abuf * 16384 + row * 64 + (((ks << 2) | khi) ^ lsw) * 8);
    }
  };
  auto readB2 = [&](bf16x8* bq, int rbuf, int np, int ks) {
#pragma unroll
    for (int j = 0; j < 2; ++j) {
      const int row = wn * 64 + (np * 2 + j) * 16 + lr;
      bq[j] = *(const bf16x8*)(BS + rbuf * 16384 + row * 64 + (((ks << 2) | khi) ^ lsw) * 8);
    }
  };
  auto mfma8 = [&](const bf16x8* bq, int mq, int np) {
    __builtin_amdgcn_s_setprio(1);
#pragma unroll
    for (int j = 0; j < 4; ++j)
#pragma unroll
      for (int n = 0; n < 2; ++n)
        acc[mq * 4 + j][np * 2 + n] =
            __builtin_amdgcn_mfma_f32_16x16x32_bf16(af[j], bq[n], acc[mq * 4 + j][np * 2 + n], 0, 0, 0);
    __builtin_amdgcn_s_setprio(0);
  };

  // ---- prologue: A(0)->AS[0]; A(1)->sa; B(0)->BS[0]; B(1)->BS[1] ----
  issueA2(0, 0); issueA2(0, 2); issueA2(0, 4); issueA2(0, 6);
  issueB1(0, 0, 0); issueB1(0, 0, 1); issueB1(0, 0, 2); issueB1(0, 0, 3);
  issueB1(1, 1, 0); issueB1(1, 1, 1); issueB1(1, 1, 2); issueB1(1, 1, 3);
  writeA2(0, 0); writeA2(0, 2); writeA2(0, 4); writeA2(0, 6);  // waits A(0) only
  issueA2(1, 0); issueA2(1, 2); issueA2(1, 4); issueA2(1, 6);  // A(1) -> sa
  asm volatile("s_waitcnt vmcnt(12)" ::: "memory");  // B(0) landed; rest in flight
  LGKM0_SCHED();
  __builtin_amdgcn_s_barrier();

  int cur = 0;
  for (int t = 0; t < NT; ++t) {
    const int rd = t % 3, st = (t + 2) % 3;
    const int tN = (t + 2 < NT) ? t + 2 : NT - 1;
    bf16x8 bq[2];
    // p0
    issueB1(st, tN, 0);
    readA(cur, 0, 0); readB2(bq, rd, 0, 0);
    __builtin_amdgcn_s_barrier(); LGKM0_SCHED();
    mfma8(bq, 0, 0); __builtin_amdgcn_s_barrier();
    // p1
    issueB1(st, tN, 1);
    readB2(bq, rd, 1, 0);
    __builtin_amdgcn_s_barrier(); LGKM0_SCHED();
    mfma8(bq, 0, 1); __builtin_amdgcn_s_barrier();
    // p2
    issueB1(st, tN, 2);
    readA(cur, 1, 0); readB2(bq, rd, 0, 0);
    __builtin_amdgcn_s_barrier(); LGKM0_SCHED();
    mfma8(bq, 1, 0); __builtin_amdgcn_s_barrier();
    // p3
    issueB1(st, tN, 3);
    readB2(bq, rd, 1, 0);
    __builtin_amdgcn_s_barrier(); LGKM0_SCHED();
    mfma8(bq, 1, 1); __builtin_amdgcn_s_barrier();
    // p4  (write A(t+1) chunk, then prefetch A(t+2) into freed regs)
    writeA2(cur ^ 1, 0); issueA2(tN, 0);
    readA(cur, 0, 1); readB2(bq, rd, 0, 1);
    __builtin_amdgcn_s_barrier(); LGKM0_SCHED();
    mfma8(bq, 0, 0); __builtin_amdgcn_s_barrier();
    // p5
    writeA2(cur ^ 1, 2); issueA2(tN, 2);
    readB2(bq, rd, 1, 1);
    __builtin_amdgcn_s_barrier(); LGKM0_SCHED();
    mfma8(bq, 0, 1); __builtin_amdgcn_s_barrier();
    // p6
    writeA2(cur ^ 1, 4); issueA2(tN, 4);
    readA(cur, 1, 1); readB2(bq, rd, 0, 1);
    __builtin_amdgcn_s_barrier(); LGKM0_SCHED();
    mfma8(bq, 1, 0); __builtin_amdgcn_s_barrier();
    // p7
    writeA2(cur ^ 1, 6); issueA2(tN, 6);
    readB2(bq, rd, 1, 1);
    __builtin_amdgcn_s_barrier(); LGKM0_SCHED();
    mfma8(bq, 1, 1);
    // boundary: NO vmcnt — prefetches stay in flight across the barrier
    __builtin_amdgcn_s_barrier();
    cur ^= 1;
  }

  // ---- epilogue: C/D map col = lane&15, row = (lane>>4)*4 + reg ----
  const int colc = lane & 15;
  const int rowb = (lane >> 4) * 4;
  if (CT) {
    // per-wave LDS transpose (two 64-row halves) -> coalesced C^T stores
    __bf16* T = (__bf16*)smem + wid * 1152;     // 16 x 72 per wave (18KB tot)
#pragma unroll
    for (int h = 0; h < 2; ++h) {
      const int mbase = mt * 256 + wm * 128 + h * 64;
#pragma unroll
      for (int ni = 0; ni < 4; ++ni) {
#pragma unroll
        for (int mi = 0; mi < 4; ++mi)
#pragma unroll
          for (int r = 0; r < 4; ++r)
            T[colc * 72 + mi * 16 + rowb + r] = (__bf16)acc[h * 4 + mi][ni][r];
        __bf16* outp = Co + (size_t)batch * BT_DIM * M
                          + (size_t)(nt * 256 + wn * 64 + ni * 16) * M + mbase + lane;
#pragma unroll
        for (int r16 = 0; r16 < 16; ++r16)
          outp[(size_t)r16 * M] = T[r16 * 72 + lane];
      }
    }
  } else {
#pragma unroll
    for (int mi = 0; mi < 8; ++mi) {
#pragma unroll
      for (int ni = 0; ni < 4; ++ni) {
        const int m = mt * 256 + wm * 128 + mi * 16 + rowb;
        const int n = nt * 256 + wn * 64 + ni * 16 + colc;
#pragma unroll
        for (int r = 0; r < 4; ++r)
          Co[((size_t)batch * M + m + r) * BT_DIM + n] = (__bf16)acc[mi][ni][r];
      }
    }
  }
}

// ---------------------------------------------------------------------------
// Kernel 3: channel mix 8->32 + squared ReLU. (unchanged)
// ---------------------------------------------------------------------------
__global__ void mix1_kernel(const __bf16* __restrict__ Y1,
                            const float* __restrict__ dw1,
                            __bf16* __restrict__ h2) {
  const int gidx = blockIdx.x * 256 + threadIdx.x;
  const int g8 = gidx & 511, bt = gidx >> 9;
  const int g0 = g8 * 8;

  float y[C_DIM][8];
#pragma unroll
  for (int c = 0; c < C_DIM; ++c) {
    bf16x8 v = *(const bf16x8*)(Y1 + ((size_t)c * BT_DIM + bt) * FH_DIM + g0);
#pragma unroll
    for (int j = 0; j < 8; ++j) y[c][j] = (float)v[j];
  }
  for (int d = 0; d < CH_DIM; ++d) {
    float s[8] = {0.f,0.f,0.f,0.f,0.f,0.f,0.f,0.f};
#pragma unroll
    for (int c = 0; c < C_DIM; ++c) {
      const float wv = dw1[d * C_DIM + c];
#pragma unroll
      for (int j = 0; j < 8; ++j) s[j] += wv * y[c][j];
    }
    bf16x8 o;
#pragma unroll
    for (int j = 0; j < 8; ++j) {
      float r = s[j] > 0.f ? s[j] : 0.f;
      o[j] = (__bf16)(r * r);
    }
    *(bf16x8*)(h2 + ((size_t)d * BT_DIM + bt) * FH_DIM + g0) = o;
  }
}

// ---------------------------------------------------------------------------
// Kernel 4: channel mix 32->8 + residual. (unchanged from R10)
// ---------------------------------------------------------------------------
__global__ void mix2_kernel(const float* __restrict__ x,
                            const __bf16* __restrict__ Y2,
                            const float* __restrict__ dw2,
                            float* __restrict__ out) {
  const int gidx = blockIdx.x * 256 + threadIdx.x;   // < 131072
  const int t4 = gidx & 63;
  const int f  = (gidx >> 6) & 1023;
  const int b  = gidx >> 16;                         // 0..1
  const int t0 = t4 * 4;

  float4 r[C_DIM];
#pragma unroll
  for (int dd = 0; dd < C_DIM; ++dd)
    r[dd] = *(const float4*)(x + ((size_t)(b * C_DIM + dd) * F_DIM + f) * T_DIM + t0);

  for (int d = 0; d < CH_DIM; ++d) {
    bf16x4 v = *(const bf16x4*)(Y2 + ((size_t)d * F_DIM + f) * BT_DIM + b * T_DIM + t0);
    const float v0 = (float)v[0], v1 = (float)v[1], v2 = (float)v[2], v3 = (float)v[3];
#pragma unroll
    for (int dd = 0; dd < C_DIM; ++dd) {
      const float w = dw2[dd * CH_DIM + d];
      r[dd].x += w * v0; r[dd].y += w * v1; r[dd].z += w * v2; r[dd].w += w * v3;
    }
  }
#pragma unroll
  for (int dd = 0; dd < C_DIM; ++dd)
    *(float4*)(out + ((size_t)(b * C_DIM + dd) * F_DIM + f) * T_DIM + t0) = r[dd];
}

// ---------------------------------------------------------------------------
extern "C" void kernel_launch(void* const* d_in, const int* in_sizes, int n_in,
                              void* d_out, int out_size, void* d_ws, size_t ws_size,
                              hipStream_t stream) {
  const float* x   = (const float*)d_in[0];
  const float* lnw = (const float*)d_in[1];
  const float* lnb = (const float*)d_in[2];
  const float* pw1 = (const float*)d_in[3];
  const float* dw1 = (const float*)d_in[4];
  const float* pw2 = (const float*)d_in[5];
  const float* dw2 = (const float*)d_in[6];
  float* out = (float*)d_out;

  char* ws = (char*)d_ws;
  __bf16* hn = (__bf16*)(ws);                    // [C][512][F]    8 MB
  __bf16* Y1 = (__bf16*)(ws + (8ULL << 20));     // [C][512][Fh]  32 MB
  __bf16* h2 = (__bf16*)(ws + (40ULL << 20));    // [Ch][512][Fh] 128 MB
  __bf16* Y2 = (__bf16*)(ws);                    // [Ch][F][512]  32 MB (reuse)

  (void)hipFuncSetAttribute((const void*)gemm_8p<5, true>,
                            hipFuncAttributeMaxDynamicSharedMemorySize, 163840);
  (void)hipFuncSetAttribute((const void*)gemm_8p<3, false>,
                            hipFuncAttributeMaxDynamicSharedMemorySize, 163840);

  ln_kernel<<<dim3(T_DIM / 16, C_DIM, B_DIM), 256, 0, stream>>>(x, lnw, lnb, hn);
  // pw1: per c: [4096 x 1024] @ [1024 x 512]^T -> Y1^T [512][4096]
  gemm_8p<5, true><<<256, 512, 163840, stream>>>(pw1, hn, Y1, FH_DIM, F_DIM);
  mix1_kernel<<<(BT_DIM * (FH_DIM / 8)) / 256, 256, 0, stream>>>(Y1, dw1, h2);
  // pw2: per d: [1024 x 4096] @ [4096 x 512]^T -> Y2 [1024][512]
  gemm_8p<3, false><<<256, 512, 163840, stream>>>(pw2, h2, Y2, F_DIM, FH_DIM);
  mix2_kernel<<<512, 256, 0, stream>>>(x, Y2, dw2, out);
}